// Round 4
// baseline (895.833 us; speedup 1.0000x reference)
//
#include <hip/hip_runtime.h>
#include <hip/hip_bf16.h>
#include <math.h>

typedef __attribute__((ext_vector_type(8))) short short8;
typedef __attribute__((ext_vector_type(4))) float f32x4;

#define DEV __device__ __forceinline__

static constexpr int Bq = 4, Lq = 4096, Ns = 8, Rk = 32;
static constexpr int Mr = Bq * Lq;                 // 16384 rows
static constexpr int NCH = 16, LCH = Lq / NCH;     // 16 chunks x 256 steps

// workspace layout (bytes) -- total 60 MiB
static constexpr size_t MiB = 1024 * 1024;
static constexpr size_t OFF_BUFA = 0;               // h -> delta_f -> ys_f -> ynorm
static constexpr size_t OFF_BUFB = 16 * MiB;        // xm (live through pass3)
static constexpr size_t OFF_BUFC = 32 * MiB;        // delta_b -> ys_b
static constexpr size_t OFF_DT   = 48 * MiB;        // dt [2 dirs x 1 MiB]
static constexpr size_t OFF_B    = 50 * MiB;        // B f32 [2 x 0.5 MiB]
static constexpr size_t OFF_C    = 51 * MiB;        // C f32 [2 x 0.5 MiB]
static constexpr size_t OFF_P    = 52 * MiB;        // chunk decay products (2 MiB)
static constexpr size_t OFF_S    = 54 * MiB;        // chunk local states (2 MiB)
static constexpr size_t OFF_HS   = 56 * MiB;        // chunk initial states (2 MiB)
static constexpr size_t OFF_CANON= 58 * MiB;        // bf16-canonicalized weights (~1.7 MiB)
// z lives in d_out until the final GEMM overwrites it.

// canonical weight segment element offsets
static constexpr int CN_INP  = 0;         // in_proj  1024x512
static constexpr int CN_OUTP = 524288;    // out_proj 512x512
static constexpr int CN_XWF  = 786432;    // x_proj_w   48x512
static constexpr int CN_XWB  = 811008;    // x_proj_w_b 48x512
static constexpr int CN_DTWF = 835584;    // dt_proj_w   512x32
static constexpr int CN_DTWB = 851968;    // dt_proj_w_b 512x32
static constexpr int CN_CWF  = 868352;    // conv_w   512x2
static constexpr int CN_CWB  = 869376;    // conv_w_b 512x2
static constexpr int CN_CBF  = 870400;    // conv_b   512
static constexpr int CN_CBB  = 870912;    // conv_b_b 512
static constexpr int CN_TOT  = 871424;

DEV float bf2f(__hip_bfloat16 v) { return __bfloat162float(v); }
DEV __hip_bfloat16 f2bf(float v) { return __float2bfloat16(v); }
DEV float sbf(short s) { __hip_bfloat16 b; *(short*)&b = s; return bf2f(b); }
DEV short bfs(float v) { __hip_bfloat16 b = f2bf(v); return *(short*)&b; }
DEV float silu(float t) { return t / (1.f + __expf(-t)); }
DEV float softplus(float v) { return fmaxf(v, 0.f) + log1pf(__expf(-fabsf(v))); }

// dtype probe: true if raw buffer looks like bf16 (vs f32). N(0,1)-scale data:
// bf16 -> all 128 u16s have plausible exponent; f32-as-u16 -> only ~60%.
DEV bool probe_is_bf16(const void* xraw) {
  const unsigned short* p = (const unsigned short*)xraw;
  int cnt = 0;
#pragma unroll
  for (int i = 0; i < 128; i++) {
    int e = (p[i] >> 7) & 0xFF;
    cnt += (e >= 90 && e <= 140) ? 1 : 0;
  }
  return cnt >= 110;
}

DEV float in_rd(const void* p, size_t i, bool isb) {
  return isb ? bf2f(((const __hip_bfloat16*)p)[i]) : ((const float*)p)[i];
}

// ---------------- canonicalize all vector-loaded weights to bf16 ----------------
__global__ void canon_kernel(const void* __restrict__ xraw,
    const void* p0, const void* p1, const void* p2, const void* p3,
    const void* p4, const void* p5, const void* p6, const void* p7,
    const void* p8, const void* p9, short* __restrict__ canon) {
  bool isb = probe_is_bf16(xraw);
  int gid = blockIdx.x * 256 + threadIdx.x;
  if (gid >= CN_TOT) return;
  const int bounds[11] = {0, CN_OUTP, CN_XWF, CN_XWB, CN_DTWF, CN_DTWB,
                          CN_CWF, CN_CWB, CN_CBF, CN_CBB, CN_TOT};
  const void* ptrs[10] = {p0, p1, p2, p3, p4, p5, p6, p7, p8, p9};
  int seg = 0;
  while (seg < 9 && gid >= bounds[seg + 1]) seg++;
  int off = gid - bounds[seg];
  canon[gid] = bfs(in_rd(ptrs[seg], (size_t)off, isb));
}

// ---------------- LayerNorm: x -> h (bf16) ----------------
__global__ void ln_kernel(const void* __restrict__ x,
                          const void* __restrict__ w,
                          const void* __restrict__ b,
                          __hip_bfloat16* __restrict__ h) {
  bool isb = probe_is_bf16(x);
  int row = blockIdx.x;
  int t = threadIdx.x;
  size_t base = (size_t)row * 512;
  float v0 = in_rd(x, base + t, isb), v1 = in_rd(x, base + t + 256, isb);
  float s = v0 + v1, ss = v0 * v0 + v1 * v1;
#pragma unroll
  for (int o = 32; o > 0; o >>= 1) { s += __shfl_down(s, o); ss += __shfl_down(ss, o); }
  __shared__ float rb[8];
  int wv = t >> 6, ln = t & 63;
  if (ln == 0) { rb[wv] = s; rb[4 + wv] = ss; }
  __syncthreads();
  if (t == 0) {
    float S = rb[0] + rb[1] + rb[2] + rb[3];
    float SS = rb[4] + rb[5] + rb[6] + rb[7];
    rb[0] = S * (1.f / 512); rb[4] = SS * (1.f / 512);
  }
  __syncthreads();
  float mu = rb[0];
  float var = rb[4] - mu * mu;
  float is = rsqrtf(var + 1e-5f);
  __hip_bfloat16* hr = h + base;
  hr[t]       = f2bf((v0 - mu) * is * in_rd(w, t, isb)       + in_rd(b, t, isb));
  hr[t + 256] = f2bf((v1 - mu) * is * in_rd(w, t + 256, isb) + in_rd(b, t + 256, isb));
}

// ---------------- big NT GEMM: C = A(Mx512) * W(Nx512)^T, synchronous LDS staging ----------------
// MODE 0: in_proj epilogue (split xm/z, both bf16).  MODE 1: out_proj epilogue (+residual, dtype-aware).
template <int MODE>
__global__ void gemm_nt(const __hip_bfloat16* __restrict__ A,
                        const __hip_bfloat16* __restrict__ W,
                        __hip_bfloat16* __restrict__ out0,
                        __hip_bfloat16* __restrict__ out1,
                        const void* __restrict__ res,
                        void* __restrict__ outv,
                        const void* __restrict__ xraw) {
  constexpr int K = 512;
  bool isb = (MODE == 1) ? probe_is_bf16(xraw) : true;
  __shared__ short lA[128 * 32];
  __shared__ short lB[128 * 32];
  const int m0 = blockIdx.y * 128, n0 = blockIdx.x * 128;
  const int tid = threadIdx.x, w = tid >> 6, lane = tid & 63;
  const int lr = lane & 15, lk = (lane >> 4) * 8;
  const int wm = (w & 1) * 64, wn = (w >> 1) * 64;
  f32x4 acc[4][4] = {};
  const int srow = w * 32 + (lane >> 2);
  const int scol = (lane & 3) * 8;
  const short* gA = (const short*)A + (size_t)(m0 + srow) * K + scol;
  const short* gB = (const short*)W + (size_t)(n0 + srow) * K + scol;
  short* lAw = &lA[w * 1024];
  short* lBw = &lB[w * 1024];
  for (int k0 = 0; k0 < K; k0 += 32) {
    short8 va0 = *(const short8*)(gA + k0);
    short8 va1 = *(const short8*)(gA + 16 * K + k0);
    short8 vb0 = *(const short8*)(gB + k0);
    short8 vb1 = *(const short8*)(gB + 16 * K + k0);
    __syncthreads();
    *(short8*)(lAw + lane * 8)       = va0;
    *(short8*)(lAw + 512 + lane * 8) = va1;
    *(short8*)(lBw + lane * 8)       = vb0;
    *(short8*)(lBw + 512 + lane * 8) = vb1;
    __syncthreads();
    short8 af[4], bfr[4];
#pragma unroll
    for (int i = 0; i < 4; i++) af[i]  = *(const short8*)&lA[(wm + i * 16 + lr) * 32 + lk];
#pragma unroll
    for (int i = 0; i < 4; i++) bfr[i] = *(const short8*)&lB[(wn + i * 16 + lr) * 32 + lk];
#pragma unroll
    for (int im = 0; im < 4; im++)
#pragma unroll
      for (int in = 0; in < 4; in++)
        acc[im][in] = __builtin_amdgcn_mfma_f32_16x16x32_bf16(af[im], bfr[in], acc[im][in], 0, 0, 0);
  }
#pragma unroll
  for (int im = 0; im < 4; im++) {
#pragma unroll
    for (int in = 0; in < 4; in++) {
      int mb = m0 + wm + im * 16 + (lane >> 4) * 4;
      int n  = n0 + wn + in * 16 + (lane & 15);
#pragma unroll
      for (int r = 0; r < 4; r++) {
        float v = acc[im][in][r];
        size_t m = (size_t)(mb + r);
        if (MODE == 0) {
          if (n < 512) out0[m * 512 + n] = f2bf(v);
          else         out1[m * 512 + (n - 512)] = f2bf(v);
        } else {
          float o = v + in_rd(res, m * 512 + n, isb);
          if (isb) ((__hip_bfloat16*)outv)[m * 512 + n] = f2bf(o);
          else     ((float*)outv)[m * 512 + n] = o;
        }
      }
    }
  }
}

// ------- x_proj with fused causal conv(k=2)+silu on A: dbc = silu(conv(xm)) * xw^T -------
__global__ void xproj_gemm(const __hip_bfloat16* __restrict__ xm,
                           const short* __restrict__ canon,
                           __hip_bfloat16* __restrict__ dt_base,
                           float* __restrict__ B_base,
                           float* __restrict__ C_base) {
  int dir = blockIdx.y;
  const short* Xm = (const short*)xm;
  const short* W  = canon + (dir ? CN_XWB : CN_XWF);
  const short* cw = canon + (dir ? CN_CWB : CN_CWF);
  const short* cb = canon + (dir ? CN_CBB : CN_CBF);
  __hip_bfloat16* dt = dt_base + (size_t)dir * Mr * Rk;
  float* Bm = B_base + (size_t)dir * Mr * Ns;
  float* Cm = C_base + (size_t)dir * Mr * Ns;
  int tid = threadIdx.x, w = tid >> 6, lane = tid & 63;
  int lr = lane & 15, lk = (lane >> 4) * 8;
  int m0 = blockIdx.x * 256 + w * 64;
  f32x4 acc[4][3] = {};
  for (int k0 = 0; k0 < 512; k0 += 32) {
    int kc = k0 + lk;
    short8 cwa  = *(const short8*)&cw[kc * 2];
    short8 cwb8 = *(const short8*)&cw[kc * 2 + 8];
    short8 cbv  = *(const short8*)&cb[kc];
    float w0v[8], w1v[8], cbf8[8];
#pragma unroll
    for (int j = 0; j < 4; j++) {
      w0v[j] = sbf(cwa[2 * j]);      w1v[j] = sbf(cwa[2 * j + 1]);
      w0v[j + 4] = sbf(cwb8[2 * j]); w1v[j + 4] = sbf(cwb8[2 * j + 1]);
    }
#pragma unroll
    for (int j = 0; j < 8; j++) cbf8[j] = sbf(cbv[j]);
    short8 af[4], bfr[3];
#pragma unroll
    for (int i = 0; i < 4; i++) {
      int m = m0 + i * 16 + lr;
      int t = m & (Lq - 1);
      short8 cur = *(const short8*)&Xm[(size_t)m * 512 + kc];
      bool have_adj = dir ? (t < Lq - 1) : (t > 0);
      int madj = dir ? (m + 1) : (m - 1);
      short8 adj = {};
      if (have_adj) adj = *(const short8*)&Xm[(size_t)madj * 512 + kc];
#pragma unroll
      for (int j = 0; j < 8; j++) {
        float cv = sbf(cur[j]);
        float av = have_adj ? sbf(adj[j]) : 0.f;
        float xc = silu(fmaf(w0v[j], av, fmaf(w1v[j], cv, cbf8[j])));
        af[i][j] = bfs(xc);
      }
    }
#pragma unroll
    for (int j = 0; j < 3; j++) bfr[j] = *(const short8*)&W[(size_t)(j * 16 + lr) * 512 + kc];
#pragma unroll
    for (int im = 0; im < 4; im++)
#pragma unroll
      for (int j = 0; j < 3; j++)
        acc[im][j] = __builtin_amdgcn_mfma_f32_16x16x32_bf16(af[im], bfr[j], acc[im][j], 0, 0, 0);
  }
#pragma unroll
  for (int im = 0; im < 4; im++) {
#pragma unroll
    for (int j = 0; j < 3; j++) {
      int mb = m0 + im * 16 + (lane >> 4) * 4;
      int col = j * 16 + (lane & 15);
#pragma unroll
      for (int r = 0; r < 4; r++) {
        float v = acc[im][j][r];
        size_t m = (size_t)(mb + r);
        if (col < 32)      dt[m * 32 + col] = f2bf(v);
        else if (col < 40) Bm[m * 8 + (col - 32)] = v;
        else               Cm[m * 8 + (col - 40)] = v;
      }
    }
  }
}

// ---------------- delta = softplus(dt(Mx32) * dtw(512x32)^T + bias) ----------------
__global__ void delta_gemm(const __hip_bfloat16* __restrict__ dt_base,
                           const short* __restrict__ canon,
                           const void* __restrict__ dtb_f,
                           const void* __restrict__ dtb_b,
                           const void* __restrict__ xraw,
                           __hip_bfloat16* __restrict__ dltA,
                           __hip_bfloat16* __restrict__ dltB) {
  bool isb = probe_is_bf16(xraw);
  int dir = blockIdx.z;
  const short* A = (const short*)(dt_base + (size_t)dir * Mr * Rk);
  const short* W = canon + (dir ? CN_DTWB : CN_DTWF);
  const void* bias = dir ? dtb_b : dtb_f;
  __hip_bfloat16* delta = dir ? dltB : dltA;
  int tid = threadIdx.x, w = tid >> 6, lane = tid & 63;
  int lr = lane & 15, lk = (lane >> 4) * 8;
  int m0 = blockIdx.y * 128 + (w & 1) * 64;
  int n0 = blockIdx.x * 128 + (w >> 1) * 64;
  f32x4 acc[4][4] = {};
  short8 af[4], bfr[4];
#pragma unroll
  for (int i = 0; i < 4; i++) af[i]  = *(const short8*)&A[(size_t)(m0 + i * 16 + lr) * 32 + lk];
#pragma unroll
  for (int i = 0; i < 4; i++) bfr[i] = *(const short8*)&W[(size_t)(n0 + i * 16 + lr) * 32 + lk];
#pragma unroll
  for (int im = 0; im < 4; im++)
#pragma unroll
    for (int in = 0; in < 4; in++)
      acc[im][in] = __builtin_amdgcn_mfma_f32_16x16x32_bf16(af[im], bfr[in], acc[im][in], 0, 0, 0);
#pragma unroll
  for (int im = 0; im < 4; im++) {
#pragma unroll
    for (int in = 0; in < 4; in++) {
      int mb = m0 + im * 16 + (lane >> 4) * 4;
      int n  = n0 + in * 16 + (lane & 15);
      float bv = in_rd(bias, n, isb);
#pragma unroll
      for (int r = 0; r < 4; r++) {
        float v = acc[im][in][r] + bv;
        delta[(size_t)(mb + r) * 512 + n] = f2bf(softplus(v));
      }
    }
  }
}

// ---------------- scan pass1: per-chunk decay product P and local state S ----------------
__global__ void scan_pass1(const __hip_bfloat16* __restrict__ dltF,
                           const __hip_bfloat16* __restrict__ dltBk,
                           const __hip_bfloat16* __restrict__ xm,
                           const short* __restrict__ canon,
                           const float* __restrict__ B_base,
                           float* __restrict__ Pb, float* __restrict__ Sb,
                           const void* __restrict__ Alog_f,
                           const void* __restrict__ Alog_b,
                           const void* __restrict__ xraw) {
  bool isb = probe_is_bf16(xraw);
  int c = blockIdx.x, dirb = blockIdx.y, dir = dirb >> 2, b = dirb & 3, d = threadIdx.x;
  const void* Al = dir ? Alog_b : Alog_f;
  float An[8];
#pragma unroll
  for (int n = 0; n < 8; n++) An[n] = -__expf(in_rd(Al, (size_t)d * Ns + n, isb));
  const short* cw = canon + (dir ? CN_CWB : CN_CWF);
  const short* cb = canon + (dir ? CN_CBB : CN_CBF);
  float w0 = sbf(cw[d * 2]), w1 = sbf(cw[d * 2 + 1]), cbv = sbf(cb[d]);
  const __hip_bfloat16* dlt = dir ? dltBk : dltF;
  const float* Bm = B_base + (size_t)dir * Mr * Ns;
  float h[8] = {}, P[8];
#pragma unroll
  for (int n = 0; n < 8; n++) P[n] = 1.f;
  int t0 = c * LCH;
  float hist;
  if (dir == 0) {
    hist = (t0 > 0) ? bf2f(xm[((size_t)b * Lq + t0 - 1) * 512 + d]) : 0.f;
  } else {
    int s0 = Lq - 1 - t0;
    hist = (s0 < Lq - 1) ? bf2f(xm[((size_t)b * Lq + s0 + 1) * 512 + d]) : 0.f;
  }
  for (int i = 0; i < LCH; i++) {
    int tt = t0 + i;
    int s = dir ? (Lq - 1 - tt) : tt;
    size_t rix = (size_t)b * Lq + s;
    float cur = bf2f(xm[rix * 512 + d]);
    float uu = silu(fmaf(w0, hist, fmaf(w1, cur, cbv)));
    hist = cur;
    float dl = bf2f(dlt[rix * 512 + d]);
    float du = dl * uu;
    const float* Br = Bm + rix * 8;
#pragma unroll
    for (int n = 0; n < 8; n++) {
      float a = __expf(dl * An[n]);
      h[n] = fmaf(a, h[n], du * Br[n]);
      P[n] *= a;
    }
  }
  size_t o = ((((size_t)dirb) * NCH + c) * 512 + d) * 8;
#pragma unroll
  for (int n = 0; n < 8; n++) { Pb[o + n] = P[n]; Sb[o + n] = h[n]; }
}

// ---------------- scan pass2: sequential chunk combine -> initial states ----------------
__global__ void scan_pass2(const float* __restrict__ Pb,
                           const float* __restrict__ Sb,
                           float* __restrict__ Hb) {
  int gid = blockIdx.x * 256 + threadIdx.x;   // 32768 = 8 * 4096
  int dirb = gid >> 12, rem = gid & 4095;
  float H = 0.f;
  for (int c = 0; c < NCH; c++) {
    size_t o = ((size_t)dirb * NCH + c) * 4096 + rem;
    Hb[o] = H;
    H = Sb[o] + Pb[o] * H;
  }
}

// ---------------- scan pass3: recompute with h0, emit y = C.h + D*u (in-place over dlt) ----------------
__global__ void scan_pass3(__hip_bfloat16* dltF,
                           __hip_bfloat16* dltBk,
                           const __hip_bfloat16* __restrict__ xm,
                           const short* __restrict__ canon,
                           const float* __restrict__ B_base,
                           const float* __restrict__ C_base,
                           const float* __restrict__ Hb,
                           const void* __restrict__ Alog_f,
                           const void* __restrict__ Alog_b,
                           const void* __restrict__ D_f,
                           const void* __restrict__ D_b,
                           const void* __restrict__ xraw) {
  bool isb = probe_is_bf16(xraw);
  int c = blockIdx.x, dirb = blockIdx.y, dir = dirb >> 2, b = dirb & 3, d = threadIdx.x;
  const void* Al = dir ? Alog_b : Alog_f;
  float An[8];
#pragma unroll
  for (int n = 0; n < 8; n++) An[n] = -__expf(in_rd(Al, (size_t)d * Ns + n, isb));
  float Dd = in_rd(dir ? D_b : D_f, d, isb);
  const short* cw = canon + (dir ? CN_CWB : CN_CWF);
  const short* cb = canon + (dir ? CN_CBB : CN_CBF);
  float w0 = sbf(cw[d * 2]), w1 = sbf(cw[d * 2 + 1]), cbv = sbf(cb[d]);
  __hip_bfloat16* dlt = dir ? dltBk : dltF;   // delta in, y out (in-place, same element)
  const float* Bm = B_base + (size_t)dir * Mr * Ns;
  const float* Cm = C_base + (size_t)dir * Mr * Ns;
  size_t o = ((((size_t)dirb) * NCH + c) * 512 + d) * 8;
  float h[8];
#pragma unroll
  for (int n = 0; n < 8; n++) h[n] = Hb[o + n];
  int t0 = c * LCH;
  float hist;
  if (dir == 0) {
    hist = (t0 > 0) ? bf2f(xm[((size_t)b * Lq + t0 - 1) * 512 + d]) : 0.f;
  } else {
    int s0 = Lq - 1 - t0;
    hist = (s0 < Lq - 1) ? bf2f(xm[((size_t)b * Lq + s0 + 1) * 512 + d]) : 0.f;
  }
  for (int i = 0; i < LCH; i++) {
    int tt = t0 + i;
    int s = dir ? (Lq - 1 - tt) : tt;
    size_t rix = (size_t)b * Lq + s;
    float cur = bf2f(xm[rix * 512 + d]);
    float uu = silu(fmaf(w0, hist, fmaf(w1, cur, cbv)));
    hist = cur;
    float dl = bf2f(dlt[rix * 512 + d]);
    float du = dl * uu;
    const float* Br = Bm + rix * 8;
    const float* Cr = Cm + rix * 8;
    float y = 0.f;
#pragma unroll
    for (int n = 0; n < 8; n++) {
      float a = __expf(dl * An[n]);
      h[n] = fmaf(a, h[n], du * Br[n]);
      y = fmaf(h[n], Cr[n], y);
    }
    dlt[rix * 512 + d] = f2bf(y + Dd * uu);
  }
}

// ---------------- gate + combine + RMSNorm -> ynorm (in-place over ys_f) ----------------
__global__ void combine_rms(const __hip_bfloat16* __restrict__ z,
                            __hip_bfloat16* ysf,   // also ynorm out
                            const __hip_bfloat16* __restrict__ ysb,
                            const void* __restrict__ rms_w,
                            const void* __restrict__ xraw) {
  bool isb = probe_is_bf16(xraw);
  int row = blockIdx.x, t = threadIdx.x;
  const __hip_bfloat16* zr = z + (size_t)row * 512;
  __hip_bfloat16* yfr = ysf + (size_t)row * 512;
  const __hip_bfloat16* ybr = ysb + (size_t)row * 512;
  float yv[2];
  float ssq = 0.f;
#pragma unroll
  for (int i = 0; i < 2; i++) {
    int d = t + i * 256;
    float zz = bf2f(zr[d]);
    float y = 0.5f * silu(zz) * (bf2f(yfr[d]) + bf2f(ybr[d]));
    yv[i] = y;
    ssq += y * y;
  }
#pragma unroll
  for (int o = 32; o > 0; o >>= 1) ssq += __shfl_down(ssq, o);
  __shared__ float rb[4];
  int wv = t >> 6, ln = t & 63;
  if (ln == 0) rb[wv] = ssq;
  __syncthreads();
  if (t == 0) rb[0] = rb[0] + rb[1] + rb[2] + rb[3];
  __syncthreads();
  float scale = rsqrtf(rb[0] * (1.f / 512) + 1e-5f);
#pragma unroll
  for (int i = 0; i < 2; i++) {
    int d = t + i * 256;
    yfr[d] = f2bf(yv[i] * scale * in_rd(rms_w, d, isb));
  }
}

extern "C" void kernel_launch(void* const* d_in, const int* in_sizes, int n_in,
                              void* d_out, int out_size, void* d_ws, size_t ws_size,
                              hipStream_t stream) {
  const void* x        = d_in[0];
  const void* ln_w     = d_in[1];
  const void* ln_b     = d_in[2];
  const void* in_proj  = d_in[3];
  const void* conv_w   = d_in[4];
  const void* conv_b   = d_in[5];
  const void* x_proj_w = d_in[6];
  const void* dt_w     = d_in[7];
  const void* dt_b     = d_in[8];
  const void* A_log    = d_in[9];
  const void* Dp       = d_in[10];
  const void* conv_w_b = d_in[11];
  const void* conv_b_b = d_in[12];
  const void* x_proj_b = d_in[13];
  const void* dt_w_b   = d_in[14];
  const void* dt_b_b   = d_in[15];
  const void* A_log_b  = d_in[16];
  const void* Dp_b     = d_in[17];
  const void* rms_w    = d_in[18];
  const void* out_w    = d_in[19];
  (void)in_sizes; (void)n_in; (void)out_size; (void)ws_size;

  char* ws = (char*)d_ws;
  __hip_bfloat16* bufA = (__hip_bfloat16*)(ws + OFF_BUFA);  // h / delta_f / ys_f / ynorm
  __hip_bfloat16* bufB = (__hip_bfloat16*)(ws + OFF_BUFB);  // xm
  __hip_bfloat16* bufC = (__hip_bfloat16*)(ws + OFF_BUFC);  // delta_b / ys_b
  __hip_bfloat16* dtb  = (__hip_bfloat16*)(ws + OFF_DT);
  float* Bb = (float*)(ws + OFF_B);
  float* Cb = (float*)(ws + OFF_C);
  float* Pb = (float*)(ws + OFF_P);
  float* Sb = (float*)(ws + OFF_S);
  float* Hb = (float*)(ws + OFF_HS);
  short* canon = (short*)(ws + OFF_CANON);
  __hip_bfloat16* z = (__hip_bfloat16*)d_out;  // parked until final GEMM overwrites

  canon_kernel<<<dim3((CN_TOT + 255) / 256), dim3(256), 0, stream>>>(
      x, in_proj, out_w, x_proj_w, x_proj_b, dt_w, dt_w_b,
      conv_w, conv_w_b, conv_b, conv_b_b, canon);
  ln_kernel<<<dim3(Mr), dim3(256), 0, stream>>>(x, ln_w, ln_b, bufA);
  gemm_nt<0><<<dim3(8, 128), dim3(256), 0, stream>>>(
      bufA, (const __hip_bfloat16*)(canon + CN_INP), bufB, z, nullptr, nullptr, x);
  xproj_gemm<<<dim3(64, 2), dim3(256), 0, stream>>>(bufB, canon, dtb, Bb, Cb);
  delta_gemm<<<dim3(4, 128, 2), dim3(256), 0, stream>>>(dtb, canon, dt_b, dt_b_b, x, bufA, bufC);
  scan_pass1<<<dim3(NCH, 8), dim3(512), 0, stream>>>(bufA, bufC, bufB, canon, Bb, Pb, Sb,
                                                     A_log, A_log_b, x);
  scan_pass2<<<dim3(128), dim3(256), 0, stream>>>(Pb, Sb, Hb);
  scan_pass3<<<dim3(NCH, 8), dim3(512), 0, stream>>>(bufA, bufC, bufB, canon, Bb, Cb, Hb,
                                                     A_log, A_log_b, Dp, Dp_b, x);
  combine_rms<<<dim3(Mr), dim3(256), 0, stream>>>(z, bufA, bufC, rms_w, x);
  gemm_nt<1><<<dim3(4, 128), dim3(256), 0, stream>>>(
      bufA, (const __hip_bfloat16*)(canon + CN_OUTP), nullptr, nullptr, x, d_out, x);
}

// Round 5
// 857.822 us; speedup vs baseline: 1.0443x; 1.0443x over previous
//
#include <hip/hip_runtime.h>
#include <hip/hip_bf16.h>
#include <math.h>

typedef __attribute__((ext_vector_type(8))) short short8;
typedef __attribute__((ext_vector_type(4))) float f32x4;

#define DEV __device__ __forceinline__

static constexpr int Bq = 4, Lq = 4096, Ns = 8, Rk = 32;
static constexpr int Mr = Bq * Lq;                 // 16384 rows
static constexpr int NCH = 16, LCH = Lq / NCH;     // 16 chunks x 256 steps

// workspace layout (bytes) -- total 60 MiB
static constexpr size_t MiB = 1024 * 1024;
static constexpr size_t OFF_BUFA = 0;               // h -> delta_f -> ys_f -> ynorm
static constexpr size_t OFF_BUFB = 16 * MiB;        // xm (live through pass3)
static constexpr size_t OFF_BUFC = 32 * MiB;        // delta_b -> ys_b
static constexpr size_t OFF_DT   = 48 * MiB;        // dt [2 dirs x 1 MiB]
static constexpr size_t OFF_B    = 50 * MiB;        // B f32 [2 x 0.5 MiB]
static constexpr size_t OFF_C    = 51 * MiB;        // C f32 [2 x 0.5 MiB]
static constexpr size_t OFF_P    = 52 * MiB;        // chunk decay products (2 MiB)
static constexpr size_t OFF_S    = 54 * MiB;        // chunk local states (2 MiB)
static constexpr size_t OFF_HS   = 56 * MiB;        // chunk initial states (2 MiB)
static constexpr size_t OFF_CANON= 58 * MiB;        // bf16-canonicalized weights (~1.7 MiB)
// z lives in d_out until the final GEMM overwrites it.

// canonical weight segment element offsets
static constexpr int CN_INP  = 0;         // in_proj  1024x512
static constexpr int CN_OUTP = 524288;    // out_proj 512x512
static constexpr int CN_XWF  = 786432;    // x_proj_w   48x512
static constexpr int CN_XWB  = 811008;    // x_proj_w_b 48x512
static constexpr int CN_DTWF = 835584;    // dt_proj_w   512x32
static constexpr int CN_DTWB = 851968;    // dt_proj_w_b 512x32
static constexpr int CN_CWF  = 868352;    // conv_w   512x2
static constexpr int CN_CWB  = 869376;    // conv_w_b 512x2
static constexpr int CN_CBF  = 870400;    // conv_b   512
static constexpr int CN_CBB  = 870912;    // conv_b_b 512
static constexpr int CN_TOT  = 871424;

DEV float bf2f(__hip_bfloat16 v) { return __bfloat162float(v); }
DEV __hip_bfloat16 f2bf(float v) { return __float2bfloat16(v); }
DEV float sbf(short s) { __hip_bfloat16 b; *(short*)&b = s; return bf2f(b); }
DEV short bfs(float v) { __hip_bfloat16 b = f2bf(v); return *(short*)&b; }
DEV float silu(float t) { return t / (1.f + __expf(-t)); }
DEV float softplus(float v) { return fmaxf(v, 0.f) + log1pf(__expf(-fabsf(v))); }

#define GLDS16(g, l) __builtin_amdgcn_global_load_lds( \
    (const __attribute__((address_space(1))) void*)(g), \
    (__attribute__((address_space(3))) void*)(l), 16, 0, 0)

// dtype probe: true if raw buffer looks like bf16 (vs f32).
DEV bool probe_is_bf16(const void* xraw) {
  const unsigned short* p = (const unsigned short*)xraw;
  int cnt = 0;
#pragma unroll
  for (int i = 0; i < 128; i++) {
    int e = (p[i] >> 7) & 0xFF;
    cnt += (e >= 90 && e <= 140) ? 1 : 0;
  }
  return cnt >= 110;
}

DEV float in_rd(const void* p, size_t i, bool isb) {
  return isb ? bf2f(((const __hip_bfloat16*)p)[i]) : ((const float*)p)[i];
}

// ---------------- canonicalize all vector-loaded weights to bf16 ----------------
__global__ void canon_kernel(const void* __restrict__ xraw,
    const void* p0, const void* p1, const void* p2, const void* p3,
    const void* p4, const void* p5, const void* p6, const void* p7,
    const void* p8, const void* p9, short* __restrict__ canon) {
  bool isb = probe_is_bf16(xraw);
  int gid = blockIdx.x * 256 + threadIdx.x;
  if (gid >= CN_TOT) return;
  const int bounds[11] = {0, CN_OUTP, CN_XWF, CN_XWB, CN_DTWF, CN_DTWB,
                          CN_CWF, CN_CWB, CN_CBF, CN_CBB, CN_TOT};
  const void* ptrs[10] = {p0, p1, p2, p3, p4, p5, p6, p7, p8, p9};
  int seg = 0;
  while (seg < 9 && gid >= bounds[seg + 1]) seg++;
  int off = gid - bounds[seg];
  canon[gid] = bfs(in_rd(ptrs[seg], (size_t)off, isb));
}

// ---------------- LayerNorm: x -> h (bf16) ----------------
__global__ void ln_kernel(const void* __restrict__ x,
                          const void* __restrict__ w,
                          const void* __restrict__ b,
                          __hip_bfloat16* __restrict__ h) {
  bool isb = probe_is_bf16(x);
  int row = blockIdx.x;
  int t = threadIdx.x;
  size_t base = (size_t)row * 512;
  float v0 = in_rd(x, base + t, isb), v1 = in_rd(x, base + t + 256, isb);
  float s = v0 + v1, ss = v0 * v0 + v1 * v1;
#pragma unroll
  for (int o = 32; o > 0; o >>= 1) { s += __shfl_down(s, o); ss += __shfl_down(ss, o); }
  __shared__ float rb[8];
  int wv = t >> 6, ln = t & 63;
  if (ln == 0) { rb[wv] = s; rb[4 + wv] = ss; }
  __syncthreads();
  if (t == 0) {
    float S = rb[0] + rb[1] + rb[2] + rb[3];
    float SS = rb[4] + rb[5] + rb[6] + rb[7];
    rb[0] = S * (1.f / 512); rb[4] = SS * (1.f / 512);
  }
  __syncthreads();
  float mu = rb[0];
  float var = rb[4] - mu * mu;
  float is = rsqrtf(var + 1e-5f);
  __hip_bfloat16* hr = h + base;
  hr[t]       = f2bf((v0 - mu) * is * in_rd(w, t, isb)       + in_rd(b, t, isb));
  hr[t + 256] = f2bf((v1 - mu) * is * in_rd(w, t + 256, isb) + in_rd(b, t + 256, isb));
}

// ---------------- big NT GEMM with global_load_lds staging ----------------
// MODE 0: in_proj epilogue (split xm/z).  MODE 1: out_proj epilogue (+residual, dtype-aware).
template <int MODE>
__global__ void gemm_nt(const __hip_bfloat16* __restrict__ A,
                        const __hip_bfloat16* __restrict__ W,
                        __hip_bfloat16* __restrict__ out0,
                        __hip_bfloat16* __restrict__ out1,
                        const void* __restrict__ res,
                        void* __restrict__ outv,
                        const void* __restrict__ xraw) {
  constexpr int K = 512;
  bool isb = (MODE == 1) ? probe_is_bf16(xraw) : true;
  __shared__ short lA[128 * 32];
  __shared__ short lB[128 * 32];
  const int m0 = blockIdx.y * 128, n0 = blockIdx.x * 128;
  const int tid = threadIdx.x, w = tid >> 6, lane = tid & 63;
  const int lr = lane & 15, lk = (lane >> 4) * 8;
  const int wm = (w & 1) * 64, wn = (w >> 1) * 64;
  f32x4 acc[4][4] = {};
  const int srow = w * 32 + (lane >> 2);
  const int scol = (lane & 3) * 8;
  const short* gA = (const short*)A + (size_t)(m0 + srow) * K + scol;
  const short* gB = (const short*)W + (size_t)(n0 + srow) * K + scol;
  short* lAw = &lA[w * 1024];
  short* lBw = &lB[w * 1024];
  for (int k0 = 0; k0 < K; k0 += 32) {
    GLDS16(gA + k0,          lAw);
    GLDS16(gA + 16 * K + k0, lAw + 512);
    GLDS16(gB + k0,          lBw);
    GLDS16(gB + 16 * K + k0, lBw + 512);
    __syncthreads();
    short8 af[4], bfr[4];
#pragma unroll
    for (int i = 0; i < 4; i++) af[i]  = *(const short8*)&lA[(wm + i * 16 + lr) * 32 + lk];
#pragma unroll
    for (int i = 0; i < 4; i++) bfr[i] = *(const short8*)&lB[(wn + i * 16 + lr) * 32 + lk];
#pragma unroll
    for (int im = 0; im < 4; im++)
#pragma unroll
      for (int in = 0; in < 4; in++)
        acc[im][in] = __builtin_amdgcn_mfma_f32_16x16x32_bf16(af[im], bfr[in], acc[im][in], 0, 0, 0);
    __syncthreads();
  }
#pragma unroll
  for (int im = 0; im < 4; im++) {
#pragma unroll
    for (int in = 0; in < 4; in++) {
      int mb = m0 + wm + im * 16 + (lane >> 4) * 4;
      int n  = n0 + wn + in * 16 + (lane & 15);
#pragma unroll
      for (int r = 0; r < 4; r++) {
        float v = acc[im][in][r];
        size_t m = (size_t)(mb + r);
        if (MODE == 0) {
          if (n < 512) out0[m * 512 + n] = f2bf(v);
          else         out1[m * 512 + (n - 512)] = f2bf(v);
        } else {
          float o = v + in_rd(res, m * 512 + n, isb);
          if (isb) ((__hip_bfloat16*)outv)[m * 512 + n] = f2bf(o);
          else     ((float*)outv)[m * 512 + n] = o;
        }
      }
    }
  }
}

// ------- x_proj with fused causal conv(k=2)+silu on A: dbc = silu(conv(xm)) * xw^T -------
// 16-row waves, grid (256, 2) for occupancy.
__global__ void xproj_gemm(const __hip_bfloat16* __restrict__ xm,
                           const short* __restrict__ canon,
                           __hip_bfloat16* __restrict__ dt_base,
                           float* __restrict__ B_base,
                           float* __restrict__ C_base) {
  int dir = blockIdx.y;
  const short* Xm = (const short*)xm;
  const short* W  = canon + (dir ? CN_XWB : CN_XWF);
  const short* cw = canon + (dir ? CN_CWB : CN_CWF);
  const short* cb = canon + (dir ? CN_CBB : CN_CBF);
  __hip_bfloat16* dt = dt_base + (size_t)dir * Mr * Rk;
  float* Bm = B_base + (size_t)dir * Mr * Ns;
  float* Cm = C_base + (size_t)dir * Mr * Ns;
  int tid = threadIdx.x, w = tid >> 6, lane = tid & 63;
  int lr = lane & 15, lk = (lane >> 4) * 8;
  int m0 = (blockIdx.x * 4 + w) * 16;
  f32x4 acc[3] = {};
  for (int k0 = 0; k0 < 512; k0 += 32) {
    int kc = k0 + lk;
    short8 cwa  = *(const short8*)&cw[kc * 2];
    short8 cwb8 = *(const short8*)&cw[kc * 2 + 8];
    short8 cbv  = *(const short8*)&cb[kc];
    float w0v[8], w1v[8], cbf8[8];
#pragma unroll
    for (int j = 0; j < 4; j++) {
      w0v[j] = sbf(cwa[2 * j]);      w1v[j] = sbf(cwa[2 * j + 1]);
      w0v[j + 4] = sbf(cwb8[2 * j]); w1v[j + 4] = sbf(cwb8[2 * j + 1]);
    }
#pragma unroll
    for (int j = 0; j < 8; j++) cbf8[j] = sbf(cbv[j]);
    short8 af, bfr[3];
    {
      int m = m0 + lr;
      int t = m & (Lq - 1);
      short8 cur = *(const short8*)&Xm[(size_t)m * 512 + kc];
      bool have_adj = dir ? (t < Lq - 1) : (t > 0);
      int madj = dir ? (m + 1) : (m - 1);
      short8 adj = {};
      if (have_adj) adj = *(const short8*)&Xm[(size_t)madj * 512 + kc];
#pragma unroll
      for (int j = 0; j < 8; j++) {
        float cv = sbf(cur[j]);
        float av = have_adj ? sbf(adj[j]) : 0.f;
        af[j] = bfs(silu(fmaf(w0v[j], av, fmaf(w1v[j], cv, cbf8[j]))));
      }
    }
#pragma unroll
    for (int j = 0; j < 3; j++) bfr[j] = *(const short8*)&W[(size_t)(j * 16 + lr) * 512 + kc];
#pragma unroll
    for (int j = 0; j < 3; j++)
      acc[j] = __builtin_amdgcn_mfma_f32_16x16x32_bf16(af, bfr[j], acc[j], 0, 0, 0);
  }
#pragma unroll
  for (int j = 0; j < 3; j++) {
    int mb = m0 + (lane >> 4) * 4;
    int col = j * 16 + (lane & 15);
#pragma unroll
    for (int r = 0; r < 4; r++) {
      float v = acc[j][r];
      size_t m = (size_t)(mb + r);
      if (col < 32)      dt[m * 32 + col] = f2bf(v);
      else if (col < 40) Bm[m * 8 + (col - 32)] = v;
      else               Cm[m * 8 + (col - 40)] = v;
    }
  }
}

// ---------------- delta = softplus(dt(Mx32) * dtw(512x32)^T + bias) ----------------
__global__ void delta_gemm(const __hip_bfloat16* __restrict__ dt_base,
                           const short* __restrict__ canon,
                           const void* __restrict__ dtb_f,
                           const void* __restrict__ dtb_b,
                           const void* __restrict__ xraw,
                           __hip_bfloat16* __restrict__ dltA,
                           __hip_bfloat16* __restrict__ dltB) {
  bool isb = probe_is_bf16(xraw);
  int dir = blockIdx.z;
  const short* A = (const short*)(dt_base + (size_t)dir * Mr * Rk);
  const short* W = canon + (dir ? CN_DTWB : CN_DTWF);
  const void* bias = dir ? dtb_b : dtb_f;
  __hip_bfloat16* delta = dir ? dltB : dltA;
  int tid = threadIdx.x, w = tid >> 6, lane = tid & 63;
  int lr = lane & 15, lk = (lane >> 4) * 8;
  int m0 = blockIdx.y * 128 + (w & 1) * 64;
  int n0 = blockIdx.x * 128 + (w >> 1) * 64;
  f32x4 acc[4][4] = {};
  short8 af[4], bfr[4];
#pragma unroll
  for (int i = 0; i < 4; i++) af[i]  = *(const short8*)&A[(size_t)(m0 + i * 16 + lr) * 32 + lk];
#pragma unroll
  for (int i = 0; i < 4; i++) bfr[i] = *(const short8*)&W[(size_t)(n0 + i * 16 + lr) * 32 + lk];
#pragma unroll
  for (int im = 0; im < 4; im++)
#pragma unroll
    for (int in = 0; in < 4; in++)
      acc[im][in] = __builtin_amdgcn_mfma_f32_16x16x32_bf16(af[im], bfr[in], acc[im][in], 0, 0, 0);
#pragma unroll
  for (int im = 0; im < 4; im++) {
#pragma unroll
    for (int in = 0; in < 4; in++) {
      int mb = m0 + im * 16 + (lane >> 4) * 4;
      int n  = n0 + in * 16 + (lane & 15);
      float bv = in_rd(bias, n, isb);
#pragma unroll
      for (int r = 0; r < 4; r++) {
        float v = acc[im][in][r] + bv;
        delta[(size_t)(mb + r) * 512 + n] = f2bf(softplus(v));
      }
    }
  }
}

// ---------------- scan pass1 (n-parallel): per-chunk decay P and local state S ----------------
// grid (NCH, 8, 8), block 512.  tid: n = tid&7, d = blockIdx.z*64 + (tid>>3).
__global__ void scan_pass1(const __hip_bfloat16* __restrict__ dltF,
                           const __hip_bfloat16* __restrict__ dltBk,
                           const __hip_bfloat16* __restrict__ xm,
                           const short* __restrict__ canon,
                           const float* __restrict__ B_base,
                           float* __restrict__ Pb, float* __restrict__ Sb,
                           const void* __restrict__ Alog_f,
                           const void* __restrict__ Alog_b,
                           const void* __restrict__ xraw) {
  bool isb = probe_is_bf16(xraw);
  int c = blockIdx.x, dirb = blockIdx.y, dir = dirb >> 2, b = dirb & 3;
  int tid = threadIdx.x;
  int n = tid & 7, d = blockIdx.z * 64 + (tid >> 3);
  const void* Al = dir ? Alog_b : Alog_f;
  float An = -__expf(in_rd(Al, (size_t)d * Ns + n, isb));
  const short* cw = canon + (dir ? CN_CWB : CN_CWF);
  const short* cb = canon + (dir ? CN_CBB : CN_CBF);
  float w0 = sbf(cw[d * 2]), w1 = sbf(cw[d * 2 + 1]), cbv = sbf(cb[d]);
  const __hip_bfloat16* dlt = dir ? dltBk : dltF;
  const float* Bm = B_base + (size_t)dir * Mr * Ns;
  float h = 0.f, P = 1.f;
  int t0 = c * LCH;
  float hist;
  if (dir == 0) {
    hist = (t0 > 0) ? bf2f(xm[((size_t)b * Lq + t0 - 1) * 512 + d]) : 0.f;
  } else {
    int s0 = Lq - 1 - t0;
    hist = (s0 < Lq - 1) ? bf2f(xm[((size_t)b * Lq + s0 + 1) * 512 + d]) : 0.f;
  }
  for (int i = 0; i < LCH; i++) {
    int tt = t0 + i;
    int s = dir ? (Lq - 1 - tt) : tt;
    size_t rix = (size_t)b * Lq + s;
    float cur = bf2f(xm[rix * 512 + d]);
    float uu = silu(fmaf(w0, hist, fmaf(w1, cur, cbv)));
    hist = cur;
    float dl = bf2f(dlt[rix * 512 + d]);
    float a = __expf(dl * An);
    h = fmaf(a, h, dl * uu * Bm[rix * 8 + n]);
    P *= a;
  }
  size_t o = ((((size_t)dirb) * NCH + c) * 512 + d) * 8 + n;
  Pb[o] = P;
  Sb[o] = h;
}

// ---------------- scan pass2: sequential chunk combine -> initial states ----------------
__global__ void scan_pass2(const float* __restrict__ Pb,
                           const float* __restrict__ Sb,
                           float* __restrict__ Hb) {
  int gid = blockIdx.x * 256 + threadIdx.x;   // 32768 = 8 * 4096
  int dirb = gid >> 12, rem = gid & 4095;
  float H = 0.f;
  for (int c = 0; c < NCH; c++) {
    size_t o = ((size_t)dirb * NCH + c) * 4096 + rem;
    Hb[o] = H;
    H = Sb[o] + Pb[o] * H;
  }
}

// ---------------- scan pass3 (n-parallel): y = C.h + D*u, in-place over dlt ----------------
__global__ void scan_pass3(__hip_bfloat16* dltF,
                           __hip_bfloat16* dltBk,
                           const __hip_bfloat16* __restrict__ xm,
                           const short* __restrict__ canon,
                           const float* __restrict__ B_base,
                           const float* __restrict__ C_base,
                           const float* __restrict__ Hb,
                           const void* __restrict__ Alog_f,
                           const void* __restrict__ Alog_b,
                           const void* __restrict__ D_f,
                           const void* __restrict__ D_b,
                           const void* __restrict__ xraw) {
  bool isb = probe_is_bf16(xraw);
  int c = blockIdx.x, dirb = blockIdx.y, dir = dirb >> 2, b = dirb & 3;
  int tid = threadIdx.x;
  int n = tid & 7, d = blockIdx.z * 64 + (tid >> 3);
  const void* Al = dir ? Alog_b : Alog_f;
  float An = -__expf(in_rd(Al, (size_t)d * Ns + n, isb));
  float Dd = in_rd(dir ? D_b : D_f, d, isb);
  const short* cw = canon + (dir ? CN_CWB : CN_CWF);
  const short* cb = canon + (dir ? CN_CBB : CN_CBF);
  float w0 = sbf(cw[d * 2]), w1 = sbf(cw[d * 2 + 1]), cbv = sbf(cb[d]);
  __hip_bfloat16* dlt = dir ? dltBk : dltF;   // delta in, y out
  const float* Bm = B_base + (size_t)dir * Mr * Ns;
  const float* Cm = C_base + (size_t)dir * Mr * Ns;
  size_t o = ((((size_t)dirb) * NCH + c) * 512 + d) * 8 + n;
  float h = Hb[o];
  int t0 = c * LCH;
  float hist;
  if (dir == 0) {
    hist = (t0 > 0) ? bf2f(xm[((size_t)b * Lq + t0 - 1) * 512 + d]) : 0.f;
  } else {
    int s0 = Lq - 1 - t0;
    hist = (s0 < Lq - 1) ? bf2f(xm[((size_t)b * Lq + s0 + 1) * 512 + d]) : 0.f;
  }
  for (int i = 0; i < LCH; i++) {
    int tt = t0 + i;
    int s = dir ? (Lq - 1 - tt) : tt;
    size_t rix = (size_t)b * Lq + s;
    float cur = bf2f(xm[rix * 512 + d]);
    float uu = silu(fmaf(w0, hist, fmaf(w1, cur, cbv)));
    hist = cur;
    float dl = bf2f(dlt[rix * 512 + d]);
    float a = __expf(dl * An);
    h = fmaf(a, h, dl * uu * Bm[rix * 8 + n]);
    float part = h * Cm[rix * 8 + n];
    part += __shfl_xor(part, 1);
    part += __shfl_xor(part, 2);
    part += __shfl_xor(part, 4);
    if (n == 0) dlt[rix * 512 + d] = f2bf(part + Dd * uu);  // wave-lockstep: reads precede write
  }
}

// ---------------- gate + combine + RMSNorm -> ynorm (in-place over ys_f) ----------------
__global__ void combine_rms(const __hip_bfloat16* __restrict__ z,
                            __hip_bfloat16* ysf,   // also ynorm out
                            const __hip_bfloat16* __restrict__ ysb,
                            const void* __restrict__ rms_w,
                            const void* __restrict__ xraw) {
  bool isb = probe_is_bf16(xraw);
  int row = blockIdx.x, t = threadIdx.x;
  const __hip_bfloat16* zr = z + (size_t)row * 512;
  __hip_bfloat16* yfr = ysf + (size_t)row * 512;
  const __hip_bfloat16* ybr = ysb + (size_t)row * 512;
  float yv[2];
  float ssq = 0.f;
#pragma unroll
  for (int i = 0; i < 2; i++) {
    int d = t + i * 256;
    float zz = bf2f(zr[d]);
    float y = 0.5f * silu(zz) * (bf2f(yfr[d]) + bf2f(ybr[d]));
    yv[i] = y;
    ssq += y * y;
  }
#pragma unroll
  for (int o = 32; o > 0; o >>= 1) ssq += __shfl_down(ssq, o);
  __shared__ float rb[4];
  int wv = t >> 6, ln = t & 63;
  if (ln == 0) rb[wv] = ssq;
  __syncthreads();
  if (t == 0) rb[0] = rb[0] + rb[1] + rb[2] + rb[3];
  __syncthreads();
  float scale = rsqrtf(rb[0] * (1.f / 512) + 1e-5f);
#pragma unroll
  for (int i = 0; i < 2; i++) {
    int d = t + i * 256;
    yfr[d] = f2bf(yv[i] * scale * in_rd(rms_w, d, isb));
  }
}

extern "C" void kernel_launch(void* const* d_in, const int* in_sizes, int n_in,
                              void* d_out, int out_size, void* d_ws, size_t ws_size,
                              hipStream_t stream) {
  const void* x        = d_in[0];
  const void* ln_w     = d_in[1];
  const void* ln_b     = d_in[2];
  const void* in_proj  = d_in[3];
  const void* conv_w   = d_in[4];
  const void* conv_b   = d_in[5];
  const void* x_proj_w = d_in[6];
  const void* dt_w     = d_in[7];
  const void* dt_b     = d_in[8];
  const void* A_log    = d_in[9];
  const void* Dp       = d_in[10];
  const void* conv_w_b = d_in[11];
  const void* conv_b_b = d_in[12];
  const void* x_proj_b = d_in[13];
  const void* dt_w_b   = d_in[14];
  const void* dt_b_b   = d_in[15];
  const void* A_log_b  = d_in[16];
  const void* Dp_b     = d_in[17];
  const void* rms_w    = d_in[18];
  const void* out_w    = d_in[19];
  (void)in_sizes; (void)n_in; (void)out_size; (void)ws_size;

  char* ws = (char*)d_ws;
  __hip_bfloat16* bufA = (__hip_bfloat16*)(ws + OFF_BUFA);  // h / delta_f / ys_f / ynorm
  __hip_bfloat16* bufB = (__hip_bfloat16*)(ws + OFF_BUFB);  // xm
  __hip_bfloat16* bufC = (__hip_bfloat16*)(ws + OFF_BUFC);  // delta_b / ys_b
  __hip_bfloat16* dtb  = (__hip_bfloat16*)(ws + OFF_DT);
  float* Bb = (float*)(ws + OFF_B);
  float* Cb = (float*)(ws + OFF_C);
  float* Pb = (float*)(ws + OFF_P);
  float* Sb = (float*)(ws + OFF_S);
  float* Hb = (float*)(ws + OFF_HS);
  short* canon = (short*)(ws + OFF_CANON);
  __hip_bfloat16* z = (__hip_bfloat16*)d_out;  // parked until final GEMM overwrites

  canon_kernel<<<dim3((CN_TOT + 255) / 256), dim3(256), 0, stream>>>(
      x, in_proj, out_w, x_proj_w, x_proj_b, dt_w, dt_w_b,
      conv_w, conv_w_b, conv_b, conv_b_b, canon);
  ln_kernel<<<dim3(Mr), dim3(256), 0, stream>>>(x, ln_w, ln_b, bufA);
  gemm_nt<0><<<dim3(8, 128), dim3(256), 0, stream>>>(
      bufA, (const __hip_bfloat16*)(canon + CN_INP), bufB, z, nullptr, nullptr, x);
  xproj_gemm<<<dim3(256, 2), dim3(256), 0, stream>>>(bufB, canon, dtb, Bb, Cb);
  delta_gemm<<<dim3(4, 128, 2), dim3(256), 0, stream>>>(dtb, canon, dt_b, dt_b_b, x, bufA, bufC);
  scan_pass1<<<dim3(NCH, 8, 8), dim3(512), 0, stream>>>(bufA, bufC, bufB, canon, Bb, Pb, Sb,
                                                        A_log, A_log_b, x);
  scan_pass2<<<dim3(128), dim3(256), 0, stream>>>(Pb, Sb, Hb);
  scan_pass3<<<dim3(NCH, 8, 8), dim3(512), 0, stream>>>(bufA, bufC, bufB, canon, Bb, Cb, Hb,
                                                        A_log, A_log_b, Dp, Dp_b, x);
  combine_rms<<<dim3(Mr), dim3(256), 0, stream>>>(z, bufA, bufC, rms_w, x);
  gemm_nt<1><<<dim3(4, 128), dim3(256), 0, stream>>>(
      bufA, (const __hip_bfloat16*)(canon + CN_OUTP), nullptr, nullptr, x, d_out, x);
}

// Round 6
// 605.424 us; speedup vs baseline: 1.4797x; 1.4169x over previous
//
#include <hip/hip_runtime.h>
#include <hip/hip_bf16.h>
#include <math.h>

typedef __attribute__((ext_vector_type(8))) short short8;
typedef __attribute__((ext_vector_type(4))) float f32x4;

#define DEV __device__ __forceinline__

static constexpr int Bq = 4, Lq = 4096, Ns = 8, Rk = 32;
static constexpr int Mr = Bq * Lq;                 // 16384 rows
static constexpr int NCH = 64, LCH = Lq / NCH;     // 64 chunks x 64 steps

// workspace layout (bytes) -- total ~53.8 MiB (known-good budget: 60 MiB)
static constexpr size_t MiB = 1024 * 1024;
static constexpr size_t OFF_BUFA = 0;               // h -> delta_f -> ys_f -> ynorm
static constexpr size_t OFF_BUFB = 16 * MiB;        // xm (live through pass3)
static constexpr size_t OFF_DT   = 32 * MiB;        // dt [2 dirs x 1 MiB]
static constexpr size_t OFF_B    = 34 * MiB;        // B f32 [2 x 0.5 MiB]
static constexpr size_t OFF_C    = 35 * MiB;        // C f32 [2 x 0.5 MiB]
static constexpr size_t OFF_P    = 36 * MiB;        // chunk decay products -> (pass2, in-place) h0 states
static constexpr size_t OFF_S    = 44 * MiB;        // chunk local states (8 MiB)
static constexpr size_t OFF_CANON= 52 * MiB;        // bf16-canonicalized weights (~1.7 MiB)
// z lives in d_out[0..16 MiB); delta_b/ys_b live in d_out[16..32 MiB) (f32 output = 32 MiB).

// canonical weight segment element offsets
static constexpr int CN_INP  = 0;         // in_proj  1024x512
static constexpr int CN_OUTP = 524288;    // out_proj 512x512
static constexpr int CN_XWF  = 786432;    // x_proj_w   48x512
static constexpr int CN_XWB  = 811008;    // x_proj_w_b 48x512
static constexpr int CN_DTWF = 835584;    // dt_proj_w   512x32
static constexpr int CN_DTWB = 851968;    // dt_proj_w_b 512x32
static constexpr int CN_CWF  = 868352;    // conv_w   512x2
static constexpr int CN_CWB  = 869376;    // conv_w_b 512x2
static constexpr int CN_CBF  = 870400;    // conv_b   512
static constexpr int CN_CBB  = 870912;    // conv_b_b 512
static constexpr int CN_TOT  = 871424;

DEV float bf2f(__hip_bfloat16 v) { return __bfloat162float(v); }
DEV __hip_bfloat16 f2bf(float v) { return __float2bfloat16(v); }
DEV float sbf(short s) { __hip_bfloat16 b; *(short*)&b = s; return bf2f(b); }
DEV short bfs(float v) { __hip_bfloat16 b = f2bf(v); return *(short*)&b; }
DEV float silu(float t) { return t / (1.f + __expf(-t)); }
DEV float softplus(float v) { return fmaxf(v, 0.f) + log1pf(__expf(-fabsf(v))); }

#define GLDS16(g, l) __builtin_amdgcn_global_load_lds( \
    (const __attribute__((address_space(1))) void*)(g), \
    (__attribute__((address_space(3))) void*)(l), 16, 0, 0)

// dtype probe: true if raw buffer looks like bf16 (vs f32).
DEV bool probe_is_bf16(const void* xraw) {
  const unsigned short* p = (const unsigned short*)xraw;
  int cnt = 0;
#pragma unroll
  for (int i = 0; i < 128; i++) {
    int e = (p[i] >> 7) & 0xFF;
    cnt += (e >= 90 && e <= 140) ? 1 : 0;
  }
  return cnt >= 110;
}

DEV float in_rd(const void* p, size_t i, bool isb) {
  return isb ? bf2f(((const __hip_bfloat16*)p)[i]) : ((const float*)p)[i];
}

// ---------------- canonicalize all vector-loaded weights to bf16 ----------------
__global__ void canon_kernel(const void* __restrict__ xraw,
    const void* p0, const void* p1, const void* p2, const void* p3,
    const void* p4, const void* p5, const void* p6, const void* p7,
    const void* p8, const void* p9, short* __restrict__ canon) {
  bool isb = probe_is_bf16(xraw);
  int gid = blockIdx.x * 256 + threadIdx.x;
  if (gid >= CN_TOT) return;
  const int bounds[11] = {0, CN_OUTP, CN_XWF, CN_XWB, CN_DTWF, CN_DTWB,
                          CN_CWF, CN_CWB, CN_CBF, CN_CBB, CN_TOT};
  const void* ptrs[10] = {p0, p1, p2, p3, p4, p5, p6, p7, p8, p9};
  int seg = 0;
  while (seg < 9 && gid >= bounds[seg + 1]) seg++;
  int off = gid - bounds[seg];
  canon[gid] = bfs(in_rd(ptrs[seg], (size_t)off, isb));
}

// ---------------- LayerNorm: x -> h (bf16) ----------------
__global__ void ln_kernel(const void* __restrict__ x,
                          const void* __restrict__ w,
                          const void* __restrict__ b,
                          __hip_bfloat16* __restrict__ h) {
  bool isb = probe_is_bf16(x);
  int row = blockIdx.x;
  int t = threadIdx.x;
  size_t base = (size_t)row * 512;
  float v0 = in_rd(x, base + t, isb), v1 = in_rd(x, base + t + 256, isb);
  float s = v0 + v1, ss = v0 * v0 + v1 * v1;
#pragma unroll
  for (int o = 32; o > 0; o >>= 1) { s += __shfl_down(s, o); ss += __shfl_down(ss, o); }
  __shared__ float rb[8];
  int wv = t >> 6, ln = t & 63;
  if (ln == 0) { rb[wv] = s; rb[4 + wv] = ss; }
  __syncthreads();
  if (t == 0) {
    float S = rb[0] + rb[1] + rb[2] + rb[3];
    float SS = rb[4] + rb[5] + rb[6] + rb[7];
    rb[0] = S * (1.f / 512); rb[4] = SS * (1.f / 512);
  }
  __syncthreads();
  float mu = rb[0];
  float var = rb[4] - mu * mu;
  float is = rsqrtf(var + 1e-5f);
  __hip_bfloat16* hr = h + base;
  hr[t]       = f2bf((v0 - mu) * is * in_rd(w, t, isb)       + in_rd(b, t, isb));
  hr[t + 256] = f2bf((v1 - mu) * is * in_rd(w, t + 256, isb) + in_rd(b, t + 256, isb));
}

// ---------------- big NT GEMM with global_load_lds staging ----------------
// MODE 0: in_proj epilogue (split xm/z).  MODE 1: out_proj epilogue (+residual, dtype-aware).
template <int MODE>
__global__ void gemm_nt(const __hip_bfloat16* __restrict__ A,
                        const __hip_bfloat16* __restrict__ W,
                        __hip_bfloat16* __restrict__ out0,
                        __hip_bfloat16* __restrict__ out1,
                        const void* __restrict__ res,
                        void* __restrict__ outv,
                        const void* __restrict__ xraw) {
  constexpr int K = 512;
  bool isb = (MODE == 1) ? probe_is_bf16(xraw) : true;
  __shared__ short lA[128 * 32];
  __shared__ short lB[128 * 32];
  const int m0 = blockIdx.y * 128, n0 = blockIdx.x * 128;
  const int tid = threadIdx.x, w = tid >> 6, lane = tid & 63;
  const int lr = lane & 15, lk = (lane >> 4) * 8;
  const int wm = (w & 1) * 64, wn = (w >> 1) * 64;
  f32x4 acc[4][4] = {};
  const int srow = w * 32 + (lane >> 2);
  const int scol = (lane & 3) * 8;
  const short* gA = (const short*)A + (size_t)(m0 + srow) * K + scol;
  const short* gB = (const short*)W + (size_t)(n0 + srow) * K + scol;
  short* lAw = &lA[w * 1024];
  short* lBw = &lB[w * 1024];
  for (int k0 = 0; k0 < K; k0 += 32) {
    GLDS16(gA + k0,          lAw);
    GLDS16(gA + 16 * K + k0, lAw + 512);
    GLDS16(gB + k0,          lBw);
    GLDS16(gB + 16 * K + k0, lBw + 512);
    __syncthreads();
    short8 af[4], bfr[4];
#pragma unroll
    for (int i = 0; i < 4; i++) af[i]  = *(const short8*)&lA[(wm + i * 16 + lr) * 32 + lk];
#pragma unroll
    for (int i = 0; i < 4; i++) bfr[i] = *(const short8*)&lB[(wn + i * 16 + lr) * 32 + lk];
#pragma unroll
    for (int im = 0; im < 4; im++)
#pragma unroll
      for (int in = 0; in < 4; in++)
        acc[im][in] = __builtin_amdgcn_mfma_f32_16x16x32_bf16(af[im], bfr[in], acc[im][in], 0, 0, 0);
    __syncthreads();
  }
#pragma unroll
  for (int im = 0; im < 4; im++) {
#pragma unroll
    for (int in = 0; in < 4; in++) {
      int mb = m0 + wm + im * 16 + (lane >> 4) * 4;
      int n  = n0 + wn + in * 16 + (lane & 15);
#pragma unroll
      for (int r = 0; r < 4; r++) {
        float v = acc[im][in][r];
        size_t m = (size_t)(mb + r);
        if (MODE == 0) {
          if (n < 512) out0[m * 512 + n] = f2bf(v);
          else         out1[m * 512 + (n - 512)] = f2bf(v);
        } else {
          float o = v + in_rd(res, m * 512 + n, isb);
          if (isb) ((__hip_bfloat16*)outv)[m * 512 + n] = f2bf(o);
          else     ((float*)outv)[m * 512 + n] = o;
        }
      }
    }
  }
}

// ------- x_proj with fused causal conv(k=2)+silu on A: dbc = silu(conv(xm)) * xw^T -------
__global__ void xproj_gemm(const __hip_bfloat16* __restrict__ xm,
                           const short* __restrict__ canon,
                           __hip_bfloat16* __restrict__ dt_base,
                           float* __restrict__ B_base,
                           float* __restrict__ C_base) {
  int dir = blockIdx.y;
  const short* Xm = (const short*)xm;
  const short* W  = canon + (dir ? CN_XWB : CN_XWF);
  const short* cw = canon + (dir ? CN_CWB : CN_CWF);
  const short* cb = canon + (dir ? CN_CBB : CN_CBF);
  __hip_bfloat16* dt = dt_base + (size_t)dir * Mr * Rk;
  float* Bm = B_base + (size_t)dir * Mr * Ns;
  float* Cm = C_base + (size_t)dir * Mr * Ns;
  int tid = threadIdx.x, w = tid >> 6, lane = tid & 63;
  int lr = lane & 15, lk = (lane >> 4) * 8;
  int m0 = (blockIdx.x * 4 + w) * 16;
  f32x4 acc[3] = {};
  for (int k0 = 0; k0 < 512; k0 += 32) {
    int kc = k0 + lk;
    short8 cwa  = *(const short8*)&cw[kc * 2];
    short8 cwb8 = *(const short8*)&cw[kc * 2 + 8];
    short8 cbv  = *(const short8*)&cb[kc];
    float w0v[8], w1v[8], cbf8[8];
#pragma unroll
    for (int j = 0; j < 4; j++) {
      w0v[j] = sbf(cwa[2 * j]);      w1v[j] = sbf(cwa[2 * j + 1]);
      w0v[j + 4] = sbf(cwb8[2 * j]); w1v[j + 4] = sbf(cwb8[2 * j + 1]);
    }
#pragma unroll
    for (int j = 0; j < 8; j++) cbf8[j] = sbf(cbv[j]);
    short8 af, bfr[3];
    {
      int m = m0 + lr;
      int t = m & (Lq - 1);
      short8 cur = *(const short8*)&Xm[(size_t)m * 512 + kc];
      bool have_adj = dir ? (t < Lq - 1) : (t > 0);
      int madj = dir ? (m + 1) : (m - 1);
      short8 adj = {};
      if (have_adj) adj = *(const short8*)&Xm[(size_t)madj * 512 + kc];
#pragma unroll
      for (int j = 0; j < 8; j++) {
        float cv = sbf(cur[j]);
        float av = have_adj ? sbf(adj[j]) : 0.f;
        af[j] = bfs(silu(fmaf(w0v[j], av, fmaf(w1v[j], cv, cbf8[j]))));
      }
    }
#pragma unroll
    for (int j = 0; j < 3; j++) bfr[j] = *(const short8*)&W[(size_t)(j * 16 + lr) * 512 + kc];
#pragma unroll
    for (int j = 0; j < 3; j++)
      acc[j] = __builtin_amdgcn_mfma_f32_16x16x32_bf16(af, bfr[j], acc[j], 0, 0, 0);
  }
#pragma unroll
  for (int j = 0; j < 3; j++) {
    int mb = m0 + (lane >> 4) * 4;
    int col = j * 16 + (lane & 15);
#pragma unroll
    for (int r = 0; r < 4; r++) {
      float v = acc[j][r];
      size_t m = (size_t)(mb + r);
      if (col < 32)      dt[m * 32 + col] = f2bf(v);
      else if (col < 40) Bm[m * 8 + (col - 32)] = v;
      else               Cm[m * 8 + (col - 40)] = v;
    }
  }
}

// ---------------- delta = softplus(dt(Mx32) * dtw(512x32)^T + bias) ----------------
__global__ void delta_gemm(const __hip_bfloat16* __restrict__ dt_base,
                           const short* __restrict__ canon,
                           const void* __restrict__ dtb_f,
                           const void* __restrict__ dtb_b,
                           const void* __restrict__ xraw,
                           __hip_bfloat16* __restrict__ dltA,
                           __hip_bfloat16* __restrict__ dltB) {
  bool isb = probe_is_bf16(xraw);
  int dir = blockIdx.z;
  const short* A = (const short*)(dt_base + (size_t)dir * Mr * Rk);
  const short* W = canon + (dir ? CN_DTWB : CN_DTWF);
  const void* bias = dir ? dtb_b : dtb_f;
  __hip_bfloat16* delta = dir ? dltB : dltA;
  int tid = threadIdx.x, w = tid >> 6, lane = tid & 63;
  int lr = lane & 15, lk = (lane >> 4) * 8;
  int m0 = blockIdx.y * 128 + (w & 1) * 64;
  int n0 = blockIdx.x * 128 + (w >> 1) * 64;
  f32x4 acc[4][4] = {};
  short8 af[4], bfr[4];
#pragma unroll
  for (int i = 0; i < 4; i++) af[i]  = *(const short8*)&A[(size_t)(m0 + i * 16 + lr) * 32 + lk];
#pragma unroll
  for (int i = 0; i < 4; i++) bfr[i] = *(const short8*)&W[(size_t)(n0 + i * 16 + lr) * 32 + lk];
#pragma unroll
  for (int im = 0; im < 4; im++)
#pragma unroll
    for (int in = 0; in < 4; in++)
      acc[im][in] = __builtin_amdgcn_mfma_f32_16x16x32_bf16(af[im], bfr[in], acc[im][in], 0, 0, 0);
#pragma unroll
  for (int im = 0; im < 4; im++) {
#pragma unroll
    for (int in = 0; in < 4; in++) {
      int mb = m0 + im * 16 + (lane >> 4) * 4;
      int n  = n0 + in * 16 + (lane & 15);
      float bv = in_rd(bias, n, isb);
#pragma unroll
      for (int r = 0; r < 4; r++) {
        float v = acc[im][in][r] + bv;
        delta[(size_t)(mb + r) * 512 + n] = f2bf(softplus(v));
      }
    }
  }
}

// ---------------- scan pass1: per-chunk decay product P and local state S (h[8]/thread) ----------------
__global__ void scan_pass1(const __hip_bfloat16* __restrict__ dltF,
                           const __hip_bfloat16* __restrict__ dltBk,
                           const __hip_bfloat16* __restrict__ xm,
                           const short* __restrict__ canon,
                           const float* __restrict__ B_base,
                           float* __restrict__ Pb, float* __restrict__ Sb,
                           const void* __restrict__ Alog_f,
                           const void* __restrict__ Alog_b,
                           const void* __restrict__ xraw) {
  bool isb = probe_is_bf16(xraw);
  int c = blockIdx.x, dirb = blockIdx.y, dir = dirb >> 2, b = dirb & 3, d = threadIdx.x;
  const void* Al = dir ? Alog_b : Alog_f;
  float An[8];
#pragma unroll
  for (int n = 0; n < 8; n++) An[n] = -__expf(in_rd(Al, (size_t)d * Ns + n, isb));
  const short* cw = canon + (dir ? CN_CWB : CN_CWF);
  const short* cb = canon + (dir ? CN_CBB : CN_CBF);
  float w0 = sbf(cw[d * 2]), w1 = sbf(cw[d * 2 + 1]), cbv = sbf(cb[d]);
  const __hip_bfloat16* dlt = dir ? dltBk : dltF;
  const float* Bm = B_base + (size_t)dir * Mr * Ns;
  float h[8] = {}, P[8];
#pragma unroll
  for (int n = 0; n < 8; n++) P[n] = 1.f;
  int t0 = c * LCH;
  float hist;
  if (dir == 0) {
    hist = (t0 > 0) ? bf2f(xm[((size_t)b * Lq + t0 - 1) * 512 + d]) : 0.f;
  } else {
    int s0 = Lq - 1 - t0;
    hist = (s0 < Lq - 1) ? bf2f(xm[((size_t)b * Lq + s0 + 1) * 512 + d]) : 0.f;
  }
  for (int i = 0; i < LCH; i++) {
    int tt = t0 + i;
    int s = dir ? (Lq - 1 - tt) : tt;
    size_t rix = (size_t)b * Lq + s;
    float cur = bf2f(xm[rix * 512 + d]);
    float uu = silu(fmaf(w0, hist, fmaf(w1, cur, cbv)));
    hist = cur;
    float dl = bf2f(dlt[rix * 512 + d]);
    float du = dl * uu;
    f32x4 B0 = *(const f32x4*)&Bm[rix * 8];
    f32x4 B1 = *(const f32x4*)&Bm[rix * 8 + 4];
#pragma unroll
    for (int n = 0; n < 8; n++) {
      float a = __expf(dl * An[n]);
      float bn = (n < 4) ? B0[n & 3] : B1[n & 3];
      h[n] = fmaf(a, h[n], du * bn);
      P[n] *= a;
    }
  }
  size_t o = ((((size_t)dirb) * NCH + c) * 512 + d) * 8;
#pragma unroll
  for (int n = 0; n < 8; n++) { Pb[o + n] = P[n]; Sb[o + n] = h[n]; }
}

// ---------------- scan pass2: sequential chunk combine; H written in-place over P ----------------
__global__ void scan_pass2(float* __restrict__ Pb,
                           const float* __restrict__ Sb) {
  int gid = blockIdx.x * 256 + threadIdx.x;   // 32768 = 8 * 4096
  int dirb = gid >> 12, rem = gid & 4095;
  float H = 0.f;
  for (int c = 0; c < NCH; c++) {
    size_t o = ((size_t)dirb * NCH + c) * 4096 + rem;
    float P = Pb[o];
    Pb[o] = H;                 // H0 for chunk c (this thread owns this column)
    H = Sb[o] + P * H;
  }
}

// ---------------- scan pass3: recompute with h0, emit y = C.h + D*u (in-place over dlt) ----------------
__global__ void scan_pass3(__hip_bfloat16* dltF,
                           __hip_bfloat16* dltBk,
                           const __hip_bfloat16* __restrict__ xm,
                           const short* __restrict__ canon,
                           const float* __restrict__ B_base,
                           const float* __restrict__ C_base,
                           const float* __restrict__ Hb,
                           const void* __restrict__ Alog_f,
                           const void* __restrict__ Alog_b,
                           const void* __restrict__ D_f,
                           const void* __restrict__ D_b,
                           const void* __restrict__ xraw) {
  bool isb = probe_is_bf16(xraw);
  int c = blockIdx.x, dirb = blockIdx.y, dir = dirb >> 2, b = dirb & 3, d = threadIdx.x;
  const void* Al = dir ? Alog_b : Alog_f;
  float An[8];
#pragma unroll
  for (int n = 0; n < 8; n++) An[n] = -__expf(in_rd(Al, (size_t)d * Ns + n, isb));
  float Dd = in_rd(dir ? D_b : D_f, d, isb);
  const short* cw = canon + (dir ? CN_CWB : CN_CWF);
  const short* cb = canon + (dir ? CN_CBB : CN_CBF);
  float w0 = sbf(cw[d * 2]), w1 = sbf(cw[d * 2 + 1]), cbv = sbf(cb[d]);
  __hip_bfloat16* dlt = dir ? dltBk : dltF;   // delta in, y out (in-place, same element)
  const float* Bm = B_base + (size_t)dir * Mr * Ns;
  const float* Cm = C_base + (size_t)dir * Mr * Ns;
  size_t o = ((((size_t)dirb) * NCH + c) * 512 + d) * 8;
  float h[8];
#pragma unroll
  for (int n = 0; n < 8; n++) h[n] = Hb[o + n];
  int t0 = c * LCH;
  float hist;
  if (dir == 0) {
    hist = (t0 > 0) ? bf2f(xm[((size_t)b * Lq + t0 - 1) * 512 + d]) : 0.f;
  } else {
    int s0 = Lq - 1 - t0;
    hist = (s0 < Lq - 1) ? bf2f(xm[((size_t)b * Lq + s0 + 1) * 512 + d]) : 0.f;
  }
  for (int i = 0; i < LCH; i++) {
    int tt = t0 + i;
    int s = dir ? (Lq - 1 - tt) : tt;
    size_t rix = (size_t)b * Lq + s;
    float cur = bf2f(xm[rix * 512 + d]);
    float uu = silu(fmaf(w0, hist, fmaf(w1, cur, cbv)));
    hist = cur;
    float dl = bf2f(dlt[rix * 512 + d]);
    float du = dl * uu;
    f32x4 B0 = *(const f32x4*)&Bm[rix * 8];
    f32x4 B1 = *(const f32x4*)&Bm[rix * 8 + 4];
    f32x4 C0 = *(const f32x4*)&Cm[rix * 8];
    f32x4 C1 = *(const f32x4*)&Cm[rix * 8 + 4];
    float y = 0.f;
#pragma unroll
    for (int n = 0; n < 8; n++) {
      float a = __expf(dl * An[n]);
      float bn = (n < 4) ? B0[n & 3] : B1[n & 3];
      float cn = (n < 4) ? C0[n & 3] : C1[n & 3];
      h[n] = fmaf(a, h[n], du * bn);
      y = fmaf(h[n], cn, y);
    }
    dlt[rix * 512 + d] = f2bf(y + Dd * uu);  // read-before-write within this thread
  }
}

// ---------------- gate + combine + RMSNorm -> ynorm (in-place over ys_f) ----------------
__global__ void combine_rms(const __hip_bfloat16* __restrict__ z,
                            __hip_bfloat16* ysf,   // also ynorm out
                            const __hip_bfloat16* __restrict__ ysb,
                            const void* __restrict__ rms_w,
                            const void* __restrict__ xraw) {
  bool isb = probe_is_bf16(xraw);
  int row = blockIdx.x, t = threadIdx.x;
  const __hip_bfloat16* zr = z + (size_t)row * 512;
  __hip_bfloat16* yfr = ysf + (size_t)row * 512;
  const __hip_bfloat16* ybr = ysb + (size_t)row * 512;
  float yv[2];
  float ssq = 0.f;
#pragma unroll
  for (int i = 0; i < 2; i++) {
    int d = t + i * 256;
    float zz = bf2f(zr[d]);
    float y = 0.5f * silu(zz) * (bf2f(yfr[d]) + bf2f(ybr[d]));
    yv[i] = y;
    ssq += y * y;
  }
#pragma unroll
  for (int o = 32; o > 0; o >>= 1) ssq += __shfl_down(ssq, o);
  __shared__ float rb[4];
  int wv = t >> 6, ln = t & 63;
  if (ln == 0) rb[wv] = ssq;
  __syncthreads();
  if (t == 0) rb[0] = rb[0] + rb[1] + rb[2] + rb[3];
  __syncthreads();
  float scale = rsqrtf(rb[0] * (1.f / 512) + 1e-5f);
#pragma unroll
  for (int i = 0; i < 2; i++) {
    int d = t + i * 256;
    yfr[d] = f2bf(yv[i] * scale * in_rd(rms_w, d, isb));
  }
}

extern "C" void kernel_launch(void* const* d_in, const int* in_sizes, int n_in,
                              void* d_out, int out_size, void* d_ws, size_t ws_size,
                              hipStream_t stream) {
  const void* x        = d_in[0];
  const void* ln_w     = d_in[1];
  const void* ln_b     = d_in[2];
  const void* in_proj  = d_in[3];
  const void* conv_w   = d_in[4];
  const void* conv_b   = d_in[5];
  const void* x_proj_w = d_in[6];
  const void* dt_w     = d_in[7];
  const void* dt_b     = d_in[8];
  const void* A_log    = d_in[9];
  const void* Dp       = d_in[10];
  const void* conv_w_b = d_in[11];
  const void* conv_b_b = d_in[12];
  const void* x_proj_b = d_in[13];
  const void* dt_w_b   = d_in[14];
  const void* dt_b_b   = d_in[15];
  const void* A_log_b  = d_in[16];
  const void* Dp_b     = d_in[17];
  const void* rms_w    = d_in[18];
  const void* out_w    = d_in[19];
  (void)in_sizes; (void)n_in; (void)out_size; (void)ws_size;

  char* ws = (char*)d_ws;
  __hip_bfloat16* bufA = (__hip_bfloat16*)(ws + OFF_BUFA);  // h / delta_f / ys_f / ynorm
  __hip_bfloat16* bufB = (__hip_bfloat16*)(ws + OFF_BUFB);  // xm
  __hip_bfloat16* dtb  = (__hip_bfloat16*)(ws + OFF_DT);
  float* Bb = (float*)(ws + OFF_B);
  float* Cb = (float*)(ws + OFF_C);
  float* Pb = (float*)(ws + OFF_P);     // P, then (pass2) H0 in place
  float* Sb = (float*)(ws + OFF_S);
  short* canon = (short*)(ws + OFF_CANON);
  __hip_bfloat16* z    = (__hip_bfloat16*)d_out;                     // d_out lower 16 MiB
  __hip_bfloat16* bufC = (__hip_bfloat16*)((char*)d_out + 16 * MiB); // d_out upper 16 MiB: delta_b/ys_b

  canon_kernel<<<dim3((CN_TOT + 255) / 256), dim3(256), 0, stream>>>(
      x, in_proj, out_w, x_proj_w, x_proj_b, dt_w, dt_w_b,
      conv_w, conv_w_b, conv_b, conv_b_b, canon);
  ln_kernel<<<dim3(Mr), dim3(256), 0, stream>>>(x, ln_w, ln_b, bufA);
  gemm_nt<0><<<dim3(8, 128), dim3(256), 0, stream>>>(
      bufA, (const __hip_bfloat16*)(canon + CN_INP), bufB, z, nullptr, nullptr, x);
  xproj_gemm<<<dim3(256, 2), dim3(256), 0, stream>>>(bufB, canon, dtb, Bb, Cb);
  delta_gemm<<<dim3(4, 128, 2), dim3(256), 0, stream>>>(dtb, canon, dt_b, dt_b_b, x, bufA, bufC);
  scan_pass1<<<dim3(NCH, 8), dim3(512), 0, stream>>>(bufA, bufC, bufB, canon, Bb, Pb, Sb,
                                                     A_log, A_log_b, x);
  scan_pass2<<<dim3(128), dim3(256), 0, stream>>>(Pb, Sb);
  scan_pass3<<<dim3(NCH, 8), dim3(512), 0, stream>>>(bufA, bufC, bufB, canon, Bb, Cb, Pb,
                                                     A_log, A_log_b, Dp, Dp_b, x);
  combine_rms<<<dim3(Mr), dim3(256), 0, stream>>>(z, bufA, bufC, rms_w, x);
  gemm_nt<1><<<dim3(4, 128), dim3(256), 0, stream>>>(
      bufA, (const __hip_bfloat16*)(canon + CN_OUTP), nullptr, nullptr, x, d_out, x);
}

// Round 7
// 408.096 us; speedup vs baseline: 2.1952x; 1.4835x over previous
//
#include <hip/hip_runtime.h>
#include <hip/hip_bf16.h>
#include <math.h>

typedef __attribute__((ext_vector_type(8))) short short8;
typedef __attribute__((ext_vector_type(4))) float f32x4;

#define DEV __device__ __forceinline__

static constexpr int Bq = 4, Lq = 4096, Ns = 8, Rk = 32;
static constexpr int Mr = Bq * Lq;                 // 16384 rows
static constexpr int NCH = 64, LCH = Lq / NCH;     // 64 chunks x 64 steps

// workspace layout (bytes) -- total ~54 MiB (known-good budget: 60 MiB)
static constexpr size_t MiB = 1024 * 1024;
static constexpr size_t OFF_BUFA = 0;               // h -> delta_f -> ys_f -> ynorm
static constexpr size_t OFF_BUFB = 16 * MiB;        // xm (live through pass3)
static constexpr size_t OFF_DT   = 32 * MiB;        // dt [2 dirs x 1 MiB]
static constexpr size_t OFF_B    = 34 * MiB;        // B f32 [2 x 0.5 MiB]
static constexpr size_t OFF_C    = 35 * MiB;        // C f32 [2 x 0.5 MiB]
static constexpr size_t OFF_P    = 36 * MiB;        // chunk decay products -> (pass2, in-place) h0
static constexpr size_t OFF_S    = 44 * MiB;        // chunk local states (8 MiB)
static constexpr size_t OFF_CANON= 52 * MiB;        // bf16-canonicalized weights (~1.7 MiB)
static constexpr size_t OFF_FLAG = 54 * MiB;        // dtype flag (int)
// z lives in d_out[0..16 MiB); delta_b/ys_b live in d_out[16..32 MiB) (f32 output = 32 MiB).

// canonical weight segment element offsets
static constexpr int CN_INP  = 0;         // in_proj  1024x512
static constexpr int CN_OUTP = 524288;    // out_proj 512x512
static constexpr int CN_XWF  = 786432;    // x_proj_w   48x512
static constexpr int CN_XWB  = 811008;    // x_proj_w_b 48x512
static constexpr int CN_DTWF = 835584;    // dt_proj_w   512x32
static constexpr int CN_DTWB = 851968;    // dt_proj_w_b 512x32
static constexpr int CN_CWF  = 868352;    // conv_w   512x2
static constexpr int CN_CWB  = 869376;    // conv_w_b 512x2
static constexpr int CN_CBF  = 870400;    // conv_b   512
static constexpr int CN_CBB  = 870912;    // conv_b_b 512
static constexpr int CN_TOT  = 871424;

DEV float bf2f(__hip_bfloat16 v) { return __bfloat162float(v); }
DEV __hip_bfloat16 f2bf(float v) { return __float2bfloat16(v); }
DEV float sbf(short s) { __hip_bfloat16 b; *(short*)&b = s; return bf2f(b); }
DEV short bfs(float v) { __hip_bfloat16 b = f2bf(v); return *(short*)&b; }
DEV float silu(float t) { return t / (1.f + __expf(-t)); }
DEV float softplus(float v) { return fmaxf(v, 0.f) + log1pf(__expf(-fabsf(v))); }

#define GLDS16(g, l) __builtin_amdgcn_global_load_lds( \
    (const __attribute__((address_space(1))) void*)(g), \
    (__attribute__((address_space(3))) void*)(l), 16, 0, 0)

DEV float in_rd(const void* p, size_t i, bool isb) {
  return isb ? bf2f(((const __hip_bfloat16*)p)[i]) : ((const float*)p)[i];
}

// ---------------- dtype probe (runs ONCE, 1 thread): bf16 vs f32 ----------------
__global__ void probe_kernel(const void* __restrict__ xraw, int* __restrict__ flag) {
  if (threadIdx.x == 0) {
    const unsigned short* p = (const unsigned short*)xraw;
    int cnt = 0;
    for (int i = 0; i < 128; i++) {
      int e = (p[i] >> 7) & 0xFF;
      cnt += (e >= 90 && e <= 140) ? 1 : 0;
    }
    *flag = (cnt >= 110) ? 1 : 0;
  }
}

// ---------------- canonicalize all vector-loaded weights to bf16 ----------------
__global__ void canon_kernel(const int* __restrict__ flag,
    const void* p0, const void* p1, const void* p2, const void* p3,
    const void* p4, const void* p5, const void* p6, const void* p7,
    const void* p8, const void* p9, short* __restrict__ canon) {
  bool isb = *flag != 0;
  int gid = blockIdx.x * 256 + threadIdx.x;
  if (gid >= CN_TOT) return;
  const int bounds[11] = {0, CN_OUTP, CN_XWF, CN_XWB, CN_DTWF, CN_DTWB,
                          CN_CWF, CN_CWB, CN_CBF, CN_CBB, CN_TOT};
  const void* ptrs[10] = {p0, p1, p2, p3, p4, p5, p6, p7, p8, p9};
  int seg = 0;
  while (seg < 9 && gid >= bounds[seg + 1]) seg++;
  int off = gid - bounds[seg];
  canon[gid] = bfs(in_rd(ptrs[seg], (size_t)off, isb));
}

// ---------------- LayerNorm: x -> h (bf16) ----------------
__global__ void ln_kernel(const void* __restrict__ x,
                          const void* __restrict__ w,
                          const void* __restrict__ b,
                          __hip_bfloat16* __restrict__ h,
                          const int* __restrict__ flag) {
  bool isb = *flag != 0;
  int row = blockIdx.x;
  int t = threadIdx.x;
  size_t base = (size_t)row * 512;
  float v0 = in_rd(x, base + t, isb), v1 = in_rd(x, base + t + 256, isb);
  float s = v0 + v1, ss = v0 * v0 + v1 * v1;
#pragma unroll
  for (int o = 32; o > 0; o >>= 1) { s += __shfl_down(s, o); ss += __shfl_down(ss, o); }
  __shared__ float rb[8];
  int wv = t >> 6, ln = t & 63;
  if (ln == 0) { rb[wv] = s; rb[4 + wv] = ss; }
  __syncthreads();
  if (t == 0) {
    float S = rb[0] + rb[1] + rb[2] + rb[3];
    float SS = rb[4] + rb[5] + rb[6] + rb[7];
    rb[0] = S * (1.f / 512); rb[4] = SS * (1.f / 512);
  }
  __syncthreads();
  float mu = rb[0];
  float var = rb[4] - mu * mu;
  float is = rsqrtf(var + 1e-5f);
  __hip_bfloat16* hr = h + base;
  hr[t]       = f2bf((v0 - mu) * is * in_rd(w, t, isb)       + in_rd(b, t, isb));
  hr[t + 256] = f2bf((v1 - mu) * is * in_rd(w, t + 256, isb) + in_rd(b, t + 256, isb));
}

// ---------------- big NT GEMM with global_load_lds staging ----------------
// MODE 0: in_proj epilogue (split xm/z).  MODE 1: out_proj epilogue (+residual, dtype-aware).
template <int MODE>
__global__ void gemm_nt(const __hip_bfloat16* __restrict__ A,
                        const __hip_bfloat16* __restrict__ W,
                        __hip_bfloat16* __restrict__ out0,
                        __hip_bfloat16* __restrict__ out1,
                        const void* __restrict__ res,
                        void* __restrict__ outv,
                        const int* __restrict__ flag) {
  constexpr int K = 512;
  bool isb = (MODE == 1) ? (*flag != 0) : true;
  __shared__ short lA[128 * 32];
  __shared__ short lB[128 * 32];
  const int m0 = blockIdx.y * 128, n0 = blockIdx.x * 128;
  const int tid = threadIdx.x, w = tid >> 6, lane = tid & 63;
  const int lr = lane & 15, lk = (lane >> 4) * 8;
  const int wm = (w & 1) * 64, wn = (w >> 1) * 64;
  f32x4 acc[4][4] = {};
  const int srow = w * 32 + (lane >> 2);
  const int scol = (lane & 3) * 8;
  const short* gA = (const short*)A + (size_t)(m0 + srow) * K + scol;
  const short* gB = (const short*)W + (size_t)(n0 + srow) * K + scol;
  short* lAw = &lA[w * 1024];
  short* lBw = &lB[w * 1024];
  for (int k0 = 0; k0 < K; k0 += 32) {
    GLDS16(gA + k0,          lAw);
    GLDS16(gA + 16 * K + k0, lAw + 512);
    GLDS16(gB + k0,          lBw);
    GLDS16(gB + 16 * K + k0, lBw + 512);
    __syncthreads();
    short8 af[4], bfr[4];
#pragma unroll
    for (int i = 0; i < 4; i++) af[i]  = *(const short8*)&lA[(wm + i * 16 + lr) * 32 + lk];
#pragma unroll
    for (int i = 0; i < 4; i++) bfr[i] = *(const short8*)&lB[(wn + i * 16 + lr) * 32 + lk];
#pragma unroll
    for (int im = 0; im < 4; im++)
#pragma unroll
      for (int in = 0; in < 4; in++)
        acc[im][in] = __builtin_amdgcn_mfma_f32_16x16x32_bf16(af[im], bfr[in], acc[im][in], 0, 0, 0);
    __syncthreads();
  }
#pragma unroll
  for (int im = 0; im < 4; im++) {
#pragma unroll
    for (int in = 0; in < 4; in++) {
      int mb = m0 + wm + im * 16 + (lane >> 4) * 4;
      int n  = n0 + wn + in * 16 + (lane & 15);
#pragma unroll
      for (int r = 0; r < 4; r++) {
        float v = acc[im][in][r];
        size_t m = (size_t)(mb + r);
        if (MODE == 0) {
          if (n < 512) out0[m * 512 + n] = f2bf(v);
          else         out1[m * 512 + (n - 512)] = f2bf(v);
        } else {
          float o = v + in_rd(res, m * 512 + n, isb);
          if (isb) ((__hip_bfloat16*)outv)[m * 512 + n] = f2bf(o);
          else     ((float*)outv)[m * 512 + n] = o;
        }
      }
    }
  }
}

// ------- x_proj with fused causal conv(k=2)+silu on A: dbc = silu(conv(xm)) * xw^T -------
__global__ void xproj_gemm(const __hip_bfloat16* __restrict__ xm,
                           const short* __restrict__ canon,
                           __hip_bfloat16* __restrict__ dt_base,
                           float* __restrict__ B_base,
                           float* __restrict__ C_base) {
  int dir = blockIdx.y;
  const short* Xm = (const short*)xm;
  const short* W  = canon + (dir ? CN_XWB : CN_XWF);
  const short* cw = canon + (dir ? CN_CWB : CN_CWF);
  const short* cb = canon + (dir ? CN_CBB : CN_CBF);
  __hip_bfloat16* dt = dt_base + (size_t)dir * Mr * Rk;
  float* Bm = B_base + (size_t)dir * Mr * Ns;
  float* Cm = C_base + (size_t)dir * Mr * Ns;
  int tid = threadIdx.x, w = tid >> 6, lane = tid & 63;
  int lr = lane & 15, lk = (lane >> 4) * 8;
  int m0 = (blockIdx.x * 4 + w) * 16;
  f32x4 acc[3] = {};
  for (int k0 = 0; k0 < 512; k0 += 32) {
    int kc = k0 + lk;
    short8 cwa  = *(const short8*)&cw[kc * 2];
    short8 cwb8 = *(const short8*)&cw[kc * 2 + 8];
    short8 cbv  = *(const short8*)&cb[kc];
    float w0v[8], w1v[8], cbf8[8];
#pragma unroll
    for (int j = 0; j < 4; j++) {
      w0v[j] = sbf(cwa[2 * j]);      w1v[j] = sbf(cwa[2 * j + 1]);
      w0v[j + 4] = sbf(cwb8[2 * j]); w1v[j + 4] = sbf(cwb8[2 * j + 1]);
    }
#pragma unroll
    for (int j = 0; j < 8; j++) cbf8[j] = sbf(cbv[j]);
    short8 af, bfr[3];
    {
      int m = m0 + lr;
      int t = m & (Lq - 1);
      short8 cur = *(const short8*)&Xm[(size_t)m * 512 + kc];
      bool have_adj = dir ? (t < Lq - 1) : (t > 0);
      int madj = dir ? (m + 1) : (m - 1);
      short8 adj = {};
      if (have_adj) adj = *(const short8*)&Xm[(size_t)madj * 512 + kc];
#pragma unroll
      for (int j = 0; j < 8; j++) {
        float cv = sbf(cur[j]);
        float av = have_adj ? sbf(adj[j]) : 0.f;
        af[j] = bfs(silu(fmaf(w0v[j], av, fmaf(w1v[j], cv, cbf8[j]))));
      }
    }
#pragma unroll
    for (int j = 0; j < 3; j++) bfr[j] = *(const short8*)&W[(size_t)(j * 16 + lr) * 512 + kc];
#pragma unroll
    for (int j = 0; j < 3; j++)
      acc[j] = __builtin_amdgcn_mfma_f32_16x16x32_bf16(af, bfr[j], acc[j], 0, 0, 0);
  }
#pragma unroll
  for (int j = 0; j < 3; j++) {
    int mb = m0 + (lane >> 4) * 4;
    int col = j * 16 + (lane & 15);
#pragma unroll
    for (int r = 0; r < 4; r++) {
      float v = acc[j][r];
      size_t m = (size_t)(mb + r);
      if (col < 32)      dt[m * 32 + col] = f2bf(v);
      else if (col < 40) Bm[m * 8 + (col - 32)] = v;
      else               Cm[m * 8 + (col - 40)] = v;
    }
  }
}

// ---------------- delta = softplus(dt(Mx32) * dtw(512x32)^T + bias) ----------------
__global__ void delta_gemm(const __hip_bfloat16* __restrict__ dt_base,
                           const short* __restrict__ canon,
                           const void* __restrict__ dtb_f,
                           const void* __restrict__ dtb_b,
                           const int* __restrict__ flag,
                           __hip_bfloat16* __restrict__ dltA,
                           __hip_bfloat16* __restrict__ dltB) {
  bool isb = *flag != 0;
  int dir = blockIdx.z;
  const short* A = (const short*)(dt_base + (size_t)dir * Mr * Rk);
  const short* W = canon + (dir ? CN_DTWB : CN_DTWF);
  const void* bias = dir ? dtb_b : dtb_f;
  __hip_bfloat16* delta = dir ? dltB : dltA;
  int tid = threadIdx.x, w = tid >> 6, lane = tid & 63;
  int lr = lane & 15, lk = (lane >> 4) * 8;
  int m0 = blockIdx.y * 128 + (w & 1) * 64;
  int n0 = blockIdx.x * 128 + (w >> 1) * 64;
  f32x4 acc[4][4] = {};
  short8 af[4], bfr[4];
#pragma unroll
  for (int i = 0; i < 4; i++) af[i]  = *(const short8*)&A[(size_t)(m0 + i * 16 + lr) * 32 + lk];
#pragma unroll
  for (int i = 0; i < 4; i++) bfr[i] = *(const short8*)&W[(size_t)(n0 + i * 16 + lr) * 32 + lk];
#pragma unroll
  for (int im = 0; im < 4; im++)
#pragma unroll
    for (int in = 0; in < 4; in++)
      acc[im][in] = __builtin_amdgcn_mfma_f32_16x16x32_bf16(af[im], bfr[in], acc[im][in], 0, 0, 0);
#pragma unroll
  for (int im = 0; im < 4; im++) {
#pragma unroll
    for (int in = 0; in < 4; in++) {
      int mb = m0 + im * 16 + (lane >> 4) * 4;
      int n  = n0 + in * 16 + (lane & 15);
      float bv = in_rd(bias, n, isb);
#pragma unroll
      for (int r = 0; r < 4; r++) {
        float v = acc[im][in][r] + bv;
        delta[(size_t)(mb + r) * 512 + n] = f2bf(softplus(v));
      }
    }
  }
}

// ---------------- scan pass1: per-chunk decay product P and local state S (h[8]/thread) ----------------
__global__ void scan_pass1(const __hip_bfloat16* __restrict__ dltF,
                           const __hip_bfloat16* __restrict__ dltBk,
                           const __hip_bfloat16* __restrict__ xm,
                           const short* __restrict__ canon,
                           const float* __restrict__ B_base,
                           float* __restrict__ Pb, float* __restrict__ Sb,
                           const void* __restrict__ Alog_f,
                           const void* __restrict__ Alog_b,
                           const int* __restrict__ flag) {
  bool isb = *flag != 0;
  int c = blockIdx.x, dirb = blockIdx.y, dir = dirb >> 2, b = dirb & 3, d = threadIdx.x;
  const void* Al = dir ? Alog_b : Alog_f;
  float An[8];
#pragma unroll
  for (int n = 0; n < 8; n++) An[n] = -__expf(in_rd(Al, (size_t)d * Ns + n, isb));
  const short* cw = canon + (dir ? CN_CWB : CN_CWF);
  const short* cb = canon + (dir ? CN_CBB : CN_CBF);
  float w0 = sbf(cw[d * 2]), w1 = sbf(cw[d * 2 + 1]), cbv = sbf(cb[d]);
  const __hip_bfloat16* dlt = dir ? dltBk : dltF;
  const float* Bm = B_base + (size_t)dir * Mr * Ns;
  float h[8] = {}, P[8];
#pragma unroll
  for (int n = 0; n < 8; n++) P[n] = 1.f;
  int t0 = c * LCH;
  float hist;
  if (dir == 0) {
    hist = (t0 > 0) ? bf2f(xm[((size_t)b * Lq + t0 - 1) * 512 + d]) : 0.f;
  } else {
    int s0 = Lq - 1 - t0;
    hist = (s0 < Lq - 1) ? bf2f(xm[((size_t)b * Lq + s0 + 1) * 512 + d]) : 0.f;
  }
  for (int i = 0; i < LCH; i++) {
    int tt = t0 + i;
    int s = dir ? (Lq - 1 - tt) : tt;
    size_t rix = (size_t)b * Lq + s;
    float cur = bf2f(xm[rix * 512 + d]);
    float uu = silu(fmaf(w0, hist, fmaf(w1, cur, cbv)));
    hist = cur;
    float dl = bf2f(dlt[rix * 512 + d]);
    float du = dl * uu;
    f32x4 B0 = *(const f32x4*)&Bm[rix * 8];
    f32x4 B1 = *(const f32x4*)&Bm[rix * 8 + 4];
#pragma unroll
    for (int n = 0; n < 8; n++) {
      float a = __expf(dl * An[n]);
      float bn = (n < 4) ? B0[n & 3] : B1[n & 3];
      h[n] = fmaf(a, h[n], du * bn);
      P[n] *= a;
    }
  }
  size_t o = ((((size_t)dirb) * NCH + c) * 512 + d) * 8;
#pragma unroll
  for (int n = 0; n < 8; n++) { Pb[o + n] = P[n]; Sb[o + n] = h[n]; }
}

// ---------------- scan pass2: sequential chunk combine; H written in-place over P ----------------
__global__ void scan_pass2(float* __restrict__ Pb,
                           const float* __restrict__ Sb) {
  int gid = blockIdx.x * 256 + threadIdx.x;   // 32768 = 8 * 4096
  int dirb = gid >> 12, rem = gid & 4095;
  float H = 0.f;
  for (int c = 0; c < NCH; c++) {
    size_t o = ((size_t)dirb * NCH + c) * 4096 + rem;
    float P = Pb[o];
    Pb[o] = H;                 // H0 for chunk c (this thread owns this column)
    H = Sb[o] + P * H;
  }
}

// ---------------- scan pass3: recompute with h0, emit y = C.h + D*u (in-place over dlt) ----------------
__global__ void scan_pass3(__hip_bfloat16* dltF,
                           __hip_bfloat16* dltBk,
                           const __hip_bfloat16* __restrict__ xm,
                           const short* __restrict__ canon,
                           const float* __restrict__ B_base,
                           const float* __restrict__ C_base,
                           const float* __restrict__ Hb,
                           const void* __restrict__ Alog_f,
                           const void* __restrict__ Alog_b,
                           const void* __restrict__ D_f,
                           const void* __restrict__ D_b,
                           const int* __restrict__ flag) {
  bool isb = *flag != 0;
  int c = blockIdx.x, dirb = blockIdx.y, dir = dirb >> 2, b = dirb & 3, d = threadIdx.x;
  const void* Al = dir ? Alog_b : Alog_f;
  float An[8];
#pragma unroll
  for (int n = 0; n < 8; n++) An[n] = -__expf(in_rd(Al, (size_t)d * Ns + n, isb));
  float Dd = in_rd(dir ? D_b : D_f, d, isb);
  const short* cw = canon + (dir ? CN_CWB : CN_CWF);
  const short* cb = canon + (dir ? CN_CBB : CN_CBF);
  float w0 = sbf(cw[d * 2]), w1 = sbf(cw[d * 2 + 1]), cbv = sbf(cb[d]);
  __hip_bfloat16* dlt = dir ? dltBk : dltF;   // delta in, y out (in-place, same element)
  const float* Bm = B_base + (size_t)dir * Mr * Ns;
  const float* Cm = C_base + (size_t)dir * Mr * Ns;
  size_t o = ((((size_t)dirb) * NCH + c) * 512 + d) * 8;
  float h[8];
#pragma unroll
  for (int n = 0; n < 8; n++) h[n] = Hb[o + n];
  int t0 = c * LCH;
  float hist;
  if (dir == 0) {
    hist = (t0 > 0) ? bf2f(xm[((size_t)b * Lq + t0 - 1) * 512 + d]) : 0.f;
  } else {
    int s0 = Lq - 1 - t0;
    hist = (s0 < Lq - 1) ? bf2f(xm[((size_t)b * Lq + s0 + 1) * 512 + d]) : 0.f;
  }
  for (int i = 0; i < LCH; i++) {
    int tt = t0 + i;
    int s = dir ? (Lq - 1 - tt) : tt;
    size_t rix = (size_t)b * Lq + s;
    float cur = bf2f(xm[rix * 512 + d]);
    float uu = silu(fmaf(w0, hist, fmaf(w1, cur, cbv)));
    hist = cur;
    float dl = bf2f(dlt[rix * 512 + d]);
    float du = dl * uu;
    f32x4 B0 = *(const f32x4*)&Bm[rix * 8];
    f32x4 B1 = *(const f32x4*)&Bm[rix * 8 + 4];
    f32x4 C0 = *(const f32x4*)&Cm[rix * 8];
    f32x4 C1 = *(const f32x4*)&Cm[rix * 8 + 4];
    float y = 0.f;
#pragma unroll
    for (int n = 0; n < 8; n++) {
      float a = __expf(dl * An[n]);
      float bn = (n < 4) ? B0[n & 3] : B1[n & 3];
      float cn = (n < 4) ? C0[n & 3] : C1[n & 3];
      h[n] = fmaf(a, h[n], du * bn);
      y = fmaf(h[n], cn, y);
    }
    dlt[rix * 512 + d] = f2bf(y + Dd * uu);  // read-before-write within this thread
  }
}

// ---------------- gate + combine + RMSNorm -> ynorm (in-place over ys_f) ----------------
__global__ void combine_rms(const __hip_bfloat16* __restrict__ z,
                            __hip_bfloat16* ysf,   // also ynorm out
                            const __hip_bfloat16* __restrict__ ysb,
                            const void* __restrict__ rms_w,
                            const int* __restrict__ flag) {
  bool isb = *flag != 0;
  int row = blockIdx.x, t = threadIdx.x;
  const __hip_bfloat16* zr = z + (size_t)row * 512;
  __hip_bfloat16* yfr = ysf + (size_t)row * 512;
  const __hip_bfloat16* ybr = ysb + (size_t)row * 512;
  float yv[2];
  float ssq = 0.f;
#pragma unroll
  for (int i = 0; i < 2; i++) {
    int d = t + i * 256;
    float zz = bf2f(zr[d]);
    float y = 0.5f * silu(zz) * (bf2f(yfr[d]) + bf2f(ybr[d]));
    yv[i] = y;
    ssq += y * y;
  }
#pragma unroll
  for (int o = 32; o > 0; o >>= 1) ssq += __shfl_down(ssq, o);
  __shared__ float rb[4];
  int wv = t >> 6, ln = t & 63;
  if (ln == 0) rb[wv] = ssq;
  __syncthreads();
  if (t == 0) rb[0] = rb[0] + rb[1] + rb[2] + rb[3];
  __syncthreads();
  float scale = rsqrtf(rb[0] * (1.f / 512) + 1e-5f);
#pragma unroll
  for (int i = 0; i < 2; i++) {
    int d = t + i * 256;
    yfr[d] = f2bf(yv[i] * scale * in_rd(rms_w, d, isb));
  }
}

extern "C" void kernel_launch(void* const* d_in, const int* in_sizes, int n_in,
                              void* d_out, int out_size, void* d_ws, size_t ws_size,
                              hipStream_t stream) {
  const void* x        = d_in[0];
  const void* ln_w     = d_in[1];
  const void* ln_b     = d_in[2];
  const void* in_proj  = d_in[3];
  const void* conv_w   = d_in[4];
  const void* conv_b   = d_in[5];
  const void* x_proj_w = d_in[6];
  const void* dt_w     = d_in[7];
  const void* dt_b     = d_in[8];
  const void* A_log    = d_in[9];
  const void* Dp       = d_in[10];
  const void* conv_w_b = d_in[11];
  const void* conv_b_b = d_in[12];
  const void* x_proj_b = d_in[13];
  const void* dt_w_b   = d_in[14];
  const void* dt_b_b   = d_in[15];
  const void* A_log_b  = d_in[16];
  const void* Dp_b     = d_in[17];
  const void* rms_w    = d_in[18];
  const void* out_w    = d_in[19];
  (void)in_sizes; (void)n_in; (void)out_size; (void)ws_size;

  char* ws = (char*)d_ws;
  __hip_bfloat16* bufA = (__hip_bfloat16*)(ws + OFF_BUFA);  // h / delta_f / ys_f / ynorm
  __hip_bfloat16* bufB = (__hip_bfloat16*)(ws + OFF_BUFB);  // xm
  __hip_bfloat16* dtb  = (__hip_bfloat16*)(ws + OFF_DT);
  float* Bb = (float*)(ws + OFF_B);
  float* Cb = (float*)(ws + OFF_C);
  float* Pb = (float*)(ws + OFF_P);     // P, then (pass2) H0 in place
  float* Sb = (float*)(ws + OFF_S);
  short* canon = (short*)(ws + OFF_CANON);
  int* flag = (int*)(ws + OFF_FLAG);
  __hip_bfloat16* z    = (__hip_bfloat16*)d_out;                     // d_out lower 16 MiB
  __hip_bfloat16* bufC = (__hip_bfloat16*)((char*)d_out + 16 * MiB); // d_out upper 16 MiB

  probe_kernel<<<dim3(1), dim3(64), 0, stream>>>(x, flag);
  canon_kernel<<<dim3((CN_TOT + 255) / 256), dim3(256), 0, stream>>>(
      flag, in_proj, out_w, x_proj_w, x_proj_b, dt_w, dt_w_b,
      conv_w, conv_w_b, conv_b, conv_b_b, canon);
  ln_kernel<<<dim3(Mr), dim3(256), 0, stream>>>(x, ln_w, ln_b, bufA, flag);
  gemm_nt<0><<<dim3(8, 128), dim3(256), 0, stream>>>(
      bufA, (const __hip_bfloat16*)(canon + CN_INP), bufB, z, nullptr, nullptr, flag);
  xproj_gemm<<<dim3(256, 2), dim3(256), 0, stream>>>(bufB, canon, dtb, Bb, Cb);
  delta_gemm<<<dim3(4, 128, 2), dim3(256), 0, stream>>>(dtb, canon, dt_b, dt_b_b, flag, bufA, bufC);
  scan_pass1<<<dim3(NCH, 8), dim3(512), 0, stream>>>(bufA, bufC, bufB, canon, Bb, Pb, Sb,
                                                     A_log, A_log_b, flag);
  scan_pass2<<<dim3(128), dim3(256), 0, stream>>>(Pb, Sb);
  scan_pass3<<<dim3(NCH, 8), dim3(512), 0, stream>>>(bufA, bufC, bufB, canon, Bb, Cb, Pb,
                                                     A_log, A_log_b, Dp, Dp_b, flag);
  combine_rms<<<dim3(Mr), dim3(256), 0, stream>>>(z, bufA, bufC, rms_w, flag);
  gemm_nt<1><<<dim3(4, 128), dim3(256), 0, stream>>>(
      bufA, (const __hip_bfloat16*)(canon + CN_OUTP), nullptr, nullptr, x, d_out, flag);
}

// Round 8
// 360.909 us; speedup vs baseline: 2.4822x; 1.1307x over previous
//
#include <hip/hip_runtime.h>
#include <hip/hip_bf16.h>
#include <math.h>

typedef __attribute__((ext_vector_type(8))) short short8;
typedef __attribute__((ext_vector_type(4))) float f32x4;

#define DEV __device__ __forceinline__

static constexpr int Bq = 4, Lq = 4096, Ns = 8, Rk = 32;
static constexpr int Mr = Bq * Lq;                 // 16384 rows
static constexpr int NCH = 64, LCH = Lq / NCH;     // 64 chunks x 64 steps

// workspace layout (bytes) -- total ~54 MiB (known-good budget: 60 MiB)
static constexpr size_t MiB = 1024 * 1024;
static constexpr size_t OFF_BUFA = 0;               // h -> delta_f -> ys_f -> ynorm
static constexpr size_t OFF_BUFB = 16 * MiB;        // xm (live through pass3)
static constexpr size_t OFF_DT   = 32 * MiB;        // dt [2 dirs x 1 MiB]
static constexpr size_t OFF_B    = 34 * MiB;        // B f32 [2 x 0.5 MiB]
static constexpr size_t OFF_C    = 35 * MiB;        // C f32 [2 x 0.5 MiB]
static constexpr size_t OFF_P    = 36 * MiB;        // chunk decay products -> (pass2, in-place) h0
static constexpr size_t OFF_S    = 44 * MiB;        // chunk local states (8 MiB)
static constexpr size_t OFF_CANON= 52 * MiB;        // bf16-canonicalized weights (~1.7 MiB)
static constexpr size_t OFF_FLAG = 54 * MiB;        // dtype flag (int)
// z lives in d_out[0..16 MiB); delta_b/ys_b live in d_out[16..32 MiB) (f32 output = 32 MiB).

// canonical weight segment element offsets
static constexpr int CN_INP  = 0;         // in_proj  1024x512
static constexpr int CN_OUTP = 524288;    // out_proj 512x512
static constexpr int CN_XWF  = 786432;    // x_proj_w   48x512
static constexpr int CN_XWB  = 811008;    // x_proj_w_b 48x512
static constexpr int CN_DTWF = 835584;    // dt_proj_w   512x32
static constexpr int CN_DTWB = 851968;    // dt_proj_w_b 512x32
static constexpr int CN_CWF  = 868352;    // conv_w   512x2
static constexpr int CN_CWB  = 869376;    // conv_w_b 512x2
static constexpr int CN_CBF  = 870400;    // conv_b   512
static constexpr int CN_CBB  = 870912;    // conv_b_b 512
static constexpr int CN_TOT  = 871424;

DEV float bf2f(__hip_bfloat16 v) { return __bfloat162float(v); }
DEV __hip_bfloat16 f2bf(float v) { return __float2bfloat16(v); }
DEV float sbf(short s) { __hip_bfloat16 b; *(short*)&b = s; return bf2f(b); }
DEV short bfs(float v) { __hip_bfloat16 b = f2bf(v); return *(short*)&b; }
DEV float silu(float t) { return t / (1.f + __expf(-t)); }
// hardware softplus: v_exp_f32 + v_log_f32; error << bf16 ulp
DEV float softplus_hw(float v) { return fmaxf(v, 0.f) + __logf(1.f + __expf(-fabsf(v))); }

#define GLDS16(g, l) __builtin_amdgcn_global_load_lds( \
    (const __attribute__((address_space(1))) void*)(g), \
    (__attribute__((address_space(3))) void*)(l), 16, 0, 0)

DEV float in_rd(const void* p, size_t i, bool isb) {
  return isb ? bf2f(((const __hip_bfloat16*)p)[i]) : ((const float*)p)[i];
}

// ---------------- dtype probe (runs ONCE, 1 thread): bf16 vs f32 ----------------
__global__ void probe_kernel(const void* __restrict__ xraw, int* __restrict__ flag) {
  if (threadIdx.x == 0) {
    const unsigned short* p = (const unsigned short*)xraw;
    int cnt = 0;
    for (int i = 0; i < 128; i++) {
      int e = (p[i] >> 7) & 0xFF;
      cnt += (e >= 90 && e <= 140) ? 1 : 0;
    }
    *flag = (cnt >= 110) ? 1 : 0;
  }
}

// ---------------- canonicalize all vector-loaded weights to bf16 ----------------
__global__ void canon_kernel(const int* __restrict__ flag,
    const void* p0, const void* p1, const void* p2, const void* p3,
    const void* p4, const void* p5, const void* p6, const void* p7,
    const void* p8, const void* p9, short* __restrict__ canon) {
  bool isb = *flag != 0;
  int gid = blockIdx.x * 256 + threadIdx.x;
  if (gid >= CN_TOT) return;
  const int bounds[11] = {0, CN_OUTP, CN_XWF, CN_XWB, CN_DTWF, CN_DTWB,
                          CN_CWF, CN_CWB, CN_CBF, CN_CBB, CN_TOT};
  const void* ptrs[10] = {p0, p1, p2, p3, p4, p5, p6, p7, p8, p9};
  int seg = 0;
  while (seg < 9 && gid >= bounds[seg + 1]) seg++;
  int off = gid - bounds[seg];
  canon[gid] = bfs(in_rd(ptrs[seg], (size_t)off, isb));
}

// ---------------- LayerNorm: x -> h (bf16) ----------------
__global__ void ln_kernel(const void* __restrict__ x,
                          const void* __restrict__ w,
                          const void* __restrict__ b,
                          __hip_bfloat16* __restrict__ h,
                          const int* __restrict__ flag) {
  bool isb = *flag != 0;
  int row = blockIdx.x;
  int t = threadIdx.x;
  size_t base = (size_t)row * 512;
  float v0 = in_rd(x, base + t, isb), v1 = in_rd(x, base + t + 256, isb);
  float s = v0 + v1, ss = v0 * v0 + v1 * v1;
#pragma unroll
  for (int o = 32; o > 0; o >>= 1) { s += __shfl_down(s, o); ss += __shfl_down(ss, o); }
  __shared__ float rb[8];
  int wv = t >> 6, ln = t & 63;
  if (ln == 0) { rb[wv] = s; rb[4 + wv] = ss; }
  __syncthreads();
  if (t == 0) {
    float S = rb[0] + rb[1] + rb[2] + rb[3];
    float SS = rb[4] + rb[5] + rb[6] + rb[7];
    rb[0] = S * (1.f / 512); rb[4] = SS * (1.f / 512);
  }
  __syncthreads();
  float mu = rb[0];
  float var = rb[4] - mu * mu;
  float is = rsqrtf(var + 1e-5f);
  __hip_bfloat16* hr = h + base;
  hr[t]       = f2bf((v0 - mu) * is * in_rd(w, t, isb)       + in_rd(b, t, isb));
  hr[t + 256] = f2bf((v1 - mu) * is * in_rd(w, t + 256, isb) + in_rd(b, t + 256, isb));
}

// ---------------- big NT GEMM with global_load_lds staging ----------------
// MODE 0: in_proj epilogue (split xm/z).  MODE 1: out_proj epilogue (+residual, dtype-aware).
template <int MODE>
__global__ void gemm_nt(const __hip_bfloat16* __restrict__ A,
                        const __hip_bfloat16* __restrict__ W,
                        __hip_bfloat16* __restrict__ out0,
                        __hip_bfloat16* __restrict__ out1,
                        const void* __restrict__ res,
                        void* __restrict__ outv,
                        const int* __restrict__ flag) {
  constexpr int K = 512;
  bool isb = (MODE == 1) ? (*flag != 0) : true;
  __shared__ short lA[128 * 32];
  __shared__ short lB[128 * 32];
  const int m0 = blockIdx.y * 128, n0 = blockIdx.x * 128;
  const int tid = threadIdx.x, w = tid >> 6, lane = tid & 63;
  const int lr = lane & 15, lk = (lane >> 4) * 8;
  const int wm = (w & 1) * 64, wn = (w >> 1) * 64;
  f32x4 acc[4][4] = {};
  const int srow = w * 32 + (lane >> 2);
  const int scol = (lane & 3) * 8;
  const short* gA = (const short*)A + (size_t)(m0 + srow) * K + scol;
  const short* gB = (const short*)W + (size_t)(n0 + srow) * K + scol;
  short* lAw = &lA[w * 1024];
  short* lBw = &lB[w * 1024];
  for (int k0 = 0; k0 < K; k0 += 32) {
    GLDS16(gA + k0,          lAw);
    GLDS16(gA + 16 * K + k0, lAw + 512);
    GLDS16(gB + k0,          lBw);
    GLDS16(gB + 16 * K + k0, lBw + 512);
    __syncthreads();
    short8 af[4], bfr[4];
#pragma unroll
    for (int i = 0; i < 4; i++) af[i]  = *(const short8*)&lA[(wm + i * 16 + lr) * 32 + lk];
#pragma unroll
    for (int i = 0; i < 4; i++) bfr[i] = *(const short8*)&lB[(wn + i * 16 + lr) * 32 + lk];
#pragma unroll
    for (int im = 0; im < 4; im++)
#pragma unroll
      for (int in = 0; in < 4; in++)
        acc[im][in] = __builtin_amdgcn_mfma_f32_16x16x32_bf16(af[im], bfr[in], acc[im][in], 0, 0, 0);
    __syncthreads();
  }
#pragma unroll
  for (int im = 0; im < 4; im++) {
#pragma unroll
    for (int in = 0; in < 4; in++) {
      int mb = m0 + wm + im * 16 + (lane >> 4) * 4;
      int n  = n0 + wn + in * 16 + (lane & 15);
#pragma unroll
      for (int r = 0; r < 4; r++) {
        float v = acc[im][in][r];
        size_t m = (size_t)(mb + r);
        if (MODE == 0) {
          if (n < 512) out0[m * 512 + n] = f2bf(v);
          else         out1[m * 512 + (n - 512)] = f2bf(v);
        } else {
          float o = v + in_rd(res, m * 512 + n, isb);
          if (isb) ((__hip_bfloat16*)outv)[m * 512 + n] = f2bf(o);
          else     ((float*)outv)[m * 512 + n] = o;
        }
      }
    }
  }
}

// ------- x_proj with fused causal conv(k=2)+silu on A: dbc = silu(conv(xm)) * xw^T -------
__global__ void xproj_gemm(const __hip_bfloat16* __restrict__ xm,
                           const short* __restrict__ canon,
                           __hip_bfloat16* __restrict__ dt_base,
                           float* __restrict__ B_base,
                           float* __restrict__ C_base) {
  int dir = blockIdx.y;
  const short* Xm = (const short*)xm;
  const short* W  = canon + (dir ? CN_XWB : CN_XWF);
  const short* cw = canon + (dir ? CN_CWB : CN_CWF);
  const short* cb = canon + (dir ? CN_CBB : CN_CBF);
  __hip_bfloat16* dt = dt_base + (size_t)dir * Mr * Rk;
  float* Bm = B_base + (size_t)dir * Mr * Ns;
  float* Cm = C_base + (size_t)dir * Mr * Ns;
  int tid = threadIdx.x, w = tid >> 6, lane = tid & 63;
  int lr = lane & 15, lk = (lane >> 4) * 8;
  int m0 = (blockIdx.x * 4 + w) * 16;
  f32x4 acc[3] = {};
  for (int k0 = 0; k0 < 512; k0 += 32) {
    int kc = k0 + lk;
    short8 cwa  = *(const short8*)&cw[kc * 2];
    short8 cwb8 = *(const short8*)&cw[kc * 2 + 8];
    short8 cbv  = *(const short8*)&cb[kc];
    float w0v[8], w1v[8], cbf8[8];
#pragma unroll
    for (int j = 0; j < 4; j++) {
      w0v[j] = sbf(cwa[2 * j]);      w1v[j] = sbf(cwa[2 * j + 1]);
      w0v[j + 4] = sbf(cwb8[2 * j]); w1v[j + 4] = sbf(cwb8[2 * j + 1]);
    }
#pragma unroll
    for (int j = 0; j < 8; j++) cbf8[j] = sbf(cbv[j]);
    short8 af, bfr[3];
    {
      int m = m0 + lr;
      int t = m & (Lq - 1);
      short8 cur = *(const short8*)&Xm[(size_t)m * 512 + kc];
      bool have_adj = dir ? (t < Lq - 1) : (t > 0);
      int madj = dir ? (m + 1) : (m - 1);
      short8 adj = {};
      if (have_adj) adj = *(const short8*)&Xm[(size_t)madj * 512 + kc];
#pragma unroll
      for (int j = 0; j < 8; j++) {
        float cv = sbf(cur[j]);
        float av = have_adj ? sbf(adj[j]) : 0.f;
        af[j] = bfs(silu(fmaf(w0v[j], av, fmaf(w1v[j], cv, cbf8[j]))));
      }
    }
#pragma unroll
    for (int j = 0; j < 3; j++) bfr[j] = *(const short8*)&W[(size_t)(j * 16 + lr) * 512 + kc];
#pragma unroll
    for (int j = 0; j < 3; j++)
      acc[j] = __builtin_amdgcn_mfma_f32_16x16x32_bf16(af, bfr[j], acc[j], 0, 0, 0);
  }
#pragma unroll
  for (int j = 0; j < 3; j++) {
    int mb = m0 + (lane >> 4) * 4;
    int col = j * 16 + (lane & 15);
#pragma unroll
    for (int r = 0; r < 4; r++) {
      float v = acc[j][r];
      size_t m = (size_t)(mb + r);
      if (col < 32)      dt[m * 32 + col] = f2bf(v);
      else if (col < 40) Bm[m * 8 + (col - 32)] = v;
      else               Cm[m * 8 + (col - 40)] = v;
    }
  }
}

// ---------------- delta = softplus(dt(Mx32) * dtw(512x32)^T + bias) ----------------
// MFMA core + hardware softplus + LDS-transposed coalesced stores.
__global__ void delta_gemm(const __hip_bfloat16* __restrict__ dt_base,
                           const short* __restrict__ canon,
                           const void* __restrict__ dtb_f,
                           const void* __restrict__ dtb_b,
                           const int* __restrict__ flag,
                           __hip_bfloat16* __restrict__ dltA,
                           __hip_bfloat16* __restrict__ dltB) {
  constexpr int LSTR = 132;   // LDS row stride (elements): quad rows -> disjoint banks
  __shared__ short lds_t[128 * LSTR];
  bool isb = *flag != 0;
  int dir = blockIdx.z;
  const short* A = (const short*)(dt_base + (size_t)dir * Mr * Rk);
  const short* W = canon + (dir ? CN_DTWB : CN_DTWF);
  const void* bias = dir ? dtb_b : dtb_f;
  __hip_bfloat16* delta = dir ? dltB : dltA;
  int tid = threadIdx.x, w = tid >> 6, lane = tid & 63;
  int lr = lane & 15, lk = (lane >> 4) * 8;
  const int mbase = blockIdx.y * 128, nbase = blockIdx.x * 128;
  int ml = (w & 1) * 64;          // wave's local row base in tile
  int nl = (w >> 1) * 64;         // wave's local col base in tile
  f32x4 acc[4][4] = {};
  short8 af[4], bfr[4];
#pragma unroll
  for (int i = 0; i < 4; i++) af[i]  = *(const short8*)&A[(size_t)(mbase + ml + i * 16 + lr) * 32 + lk];
#pragma unroll
  for (int i = 0; i < 4; i++) bfr[i] = *(const short8*)&W[(size_t)(nbase + nl + i * 16 + lr) * 32 + lk];
#pragma unroll
  for (int im = 0; im < 4; im++)
#pragma unroll
    for (int in = 0; in < 4; in++)
      acc[im][in] = __builtin_amdgcn_mfma_f32_16x16x32_bf16(af[im], bfr[in], acc[im][in], 0, 0, 0);
  // softplus -> LDS tile
#pragma unroll
  for (int im = 0; im < 4; im++) {
#pragma unroll
    for (int in = 0; in < 4; in++) {
      int rl = ml + im * 16 + (lane >> 4) * 4;     // local row
      int cl = nl + in * 16 + (lane & 15);         // local col
      float bv = in_rd(bias, nbase + cl, isb);
#pragma unroll
      for (int r = 0; r < 4; r++)
        lds_t[(rl + r) * LSTR + cl] = bfs(softplus_hw(acc[im][in][r] + bv));
    }
  }
  __syncthreads();
  // coalesced store: per iter, each wave writes 4 rows x 128 cols (16 lanes x short8 = 256B/row)
#pragma unroll
  for (int it = 0; it < 8; it++) {
    int row = w * 32 + it * 4 + (lane >> 4);
    short8 vals = *(const short8*)&lds_t[row * LSTR + (lane & 15) * 8];
    *(short8*)((short*)delta + (size_t)(mbase + row) * 512 + nbase + (lane & 15) * 8) = vals;
  }
}

// ---------------- scan pass1: per-chunk decay product P and local state S (h[8]/thread) ----------------
__global__ void scan_pass1(const __hip_bfloat16* __restrict__ dltF,
                           const __hip_bfloat16* __restrict__ dltBk,
                           const __hip_bfloat16* __restrict__ xm,
                           const short* __restrict__ canon,
                           const float* __restrict__ B_base,
                           float* __restrict__ Pb, float* __restrict__ Sb,
                           const void* __restrict__ Alog_f,
                           const void* __restrict__ Alog_b,
                           const int* __restrict__ flag) {
  bool isb = *flag != 0;
  int c = blockIdx.x, dirb = blockIdx.y, dir = dirb >> 2, b = dirb & 3, d = threadIdx.x;
  const void* Al = dir ? Alog_b : Alog_f;
  float An[8];
#pragma unroll
  for (int n = 0; n < 8; n++) An[n] = -__expf(in_rd(Al, (size_t)d * Ns + n, isb));
  const short* cw = canon + (dir ? CN_CWB : CN_CWF);
  const short* cb = canon + (dir ? CN_CBB : CN_CBF);
  float w0 = sbf(cw[d * 2]), w1 = sbf(cw[d * 2 + 1]), cbv = sbf(cb[d]);
  const __hip_bfloat16* dlt = dir ? dltBk : dltF;
  const float* Bm = B_base + (size_t)dir * Mr * Ns;
  float h[8] = {}, P[8];
#pragma unroll
  for (int n = 0; n < 8; n++) P[n] = 1.f;
  int t0 = c * LCH;
  float hist;
  if (dir == 0) {
    hist = (t0 > 0) ? bf2f(xm[((size_t)b * Lq + t0 - 1) * 512 + d]) : 0.f;
  } else {
    int s0 = Lq - 1 - t0;
    hist = (s0 < Lq - 1) ? bf2f(xm[((size_t)b * Lq + s0 + 1) * 512 + d]) : 0.f;
  }
  for (int i = 0; i < LCH; i++) {
    int tt = t0 + i;
    int s = dir ? (Lq - 1 - tt) : tt;
    size_t rix = (size_t)b * Lq + s;
    float cur = bf2f(xm[rix * 512 + d]);
    float uu = silu(fmaf(w0, hist, fmaf(w1, cur, cbv)));
    hist = cur;
    float dl = bf2f(dlt[rix * 512 + d]);
    float du = dl * uu;
    f32x4 B0 = *(const f32x4*)&Bm[rix * 8];
    f32x4 B1 = *(const f32x4*)&Bm[rix * 8 + 4];
#pragma unroll
    for (int n = 0; n < 8; n++) {
      float a = __expf(dl * An[n]);
      float bn = (n < 4) ? B0[n & 3] : B1[n & 3];
      h[n] = fmaf(a, h[n], du * bn);
      P[n] *= a;
    }
  }
  size_t o = ((((size_t)dirb) * NCH + c) * 512 + d) * 8;
#pragma unroll
  for (int n = 0; n < 8; n++) { Pb[o + n] = P[n]; Sb[o + n] = h[n]; }
}

// ---------------- scan pass2: sequential chunk combine; H written in-place over P ----------------
__global__ void scan_pass2(float* __restrict__ Pb,
                           const float* __restrict__ Sb) {
  int gid = blockIdx.x * 256 + threadIdx.x;   // 32768 = 8 * 4096
  int dirb = gid >> 12, rem = gid & 4095;
  float H = 0.f;
  for (int c = 0; c < NCH; c++) {
    size_t o = ((size_t)dirb * NCH + c) * 4096 + rem;
    float P = Pb[o];
    Pb[o] = H;                 // H0 for chunk c (this thread owns this column)
    H = Sb[o] + P * H;
  }
}

// ---------------- scan pass3: recompute with h0, emit y = C.h + D*u (in-place over dlt) ----------------
__global__ void scan_pass3(__hip_bfloat16* dltF,
                           __hip_bfloat16* dltBk,
                           const __hip_bfloat16* __restrict__ xm,
                           const short* __restrict__ canon,
                           const float* __restrict__ B_base,
                           const float* __restrict__ C_base,
                           const float* __restrict__ Hb,
                           const void* __restrict__ Alog_f,
                           const void* __restrict__ Alog_b,
                           const void* __restrict__ D_f,
                           const void* __restrict__ D_b,
                           const int* __restrict__ flag) {
  bool isb = *flag != 0;
  int c = blockIdx.x, dirb = blockIdx.y, dir = dirb >> 2, b = dirb & 3, d = threadIdx.x;
  const void* Al = dir ? Alog_b : Alog_f;
  float An[8];
#pragma unroll
  for (int n = 0; n < 8; n++) An[n] = -__expf(in_rd(Al, (size_t)d * Ns + n, isb));
  float Dd = in_rd(dir ? D_b : D_f, d, isb);
  const short* cw = canon + (dir ? CN_CWB : CN_CWF);
  const short* cb = canon + (dir ? CN_CBB : CN_CBF);
  float w0 = sbf(cw[d * 2]), w1 = sbf(cw[d * 2 + 1]), cbv = sbf(cb[d]);
  __hip_bfloat16* dlt = dir ? dltBk : dltF;   // delta in, y out (in-place, same element)
  const float* Bm = B_base + (size_t)dir * Mr * Ns;
  const float* Cm = C_base + (size_t)dir * Mr * Ns;
  size_t o = ((((size_t)dirb) * NCH + c) * 512 + d) * 8;
  float h[8];
#pragma unroll
  for (int n = 0; n < 8; n++) h[n] = Hb[o + n];
  int t0 = c * LCH;
  float hist;
  if (dir == 0) {
    hist = (t0 > 0) ? bf2f(xm[((size_t)b * Lq + t0 - 1) * 512 + d]) : 0.f;
  } else {
    int s0 = Lq - 1 - t0;
    hist = (s0 < Lq - 1) ? bf2f(xm[((size_t)b * Lq + s0 + 1) * 512 + d]) : 0.f;
  }
  for (int i = 0; i < LCH; i++) {
    int tt = t0 + i;
    int s = dir ? (Lq - 1 - tt) : tt;
    size_t rix = (size_t)b * Lq + s;
    float cur = bf2f(xm[rix * 512 + d]);
    float uu = silu(fmaf(w0, hist, fmaf(w1, cur, cbv)));
    hist = cur;
    float dl = bf2f(dlt[rix * 512 + d]);
    float du = dl * uu;
    f32x4 B0 = *(const f32x4*)&Bm[rix * 8];
    f32x4 B1 = *(const f32x4*)&Bm[rix * 8 + 4];
    f32x4 C0 = *(const f32x4*)&Cm[rix * 8];
    f32x4 C1 = *(const f32x4*)&Cm[rix * 8 + 4];
    float y = 0.f;
#pragma unroll
    for (int n = 0; n < 8; n++) {
      float a = __expf(dl * An[n]);
      float bn = (n < 4) ? B0[n & 3] : B1[n & 3];
      float cn = (n < 4) ? C0[n & 3] : C1[n & 3];
      h[n] = fmaf(a, h[n], du * bn);
      y = fmaf(h[n], cn, y);
    }
    dlt[rix * 512 + d] = f2bf(y + Dd * uu);  // read-before-write within this thread
  }
}

// ---------------- gate + combine + RMSNorm -> ynorm (in-place over ys_f) ----------------
__global__ void combine_rms(const __hip_bfloat16* __restrict__ z,
                            __hip_bfloat16* ysf,   // also ynorm out
                            const __hip_bfloat16* __restrict__ ysb,
                            const void* __restrict__ rms_w,
                            const int* __restrict__ flag) {
  bool isb = *flag != 0;
  int row = blockIdx.x, t = threadIdx.x;
  const __hip_bfloat16* zr = z + (size_t)row * 512;
  __hip_bfloat16* yfr = ysf + (size_t)row * 512;
  const __hip_bfloat16* ybr = ysb + (size_t)row * 512;
  float yv[2];
  float ssq = 0.f;
#pragma unroll
  for (int i = 0; i < 2; i++) {
    int d = t + i * 256;
    float zz = bf2f(zr[d]);
    float y = 0.5f * silu(zz) * (bf2f(yfr[d]) + bf2f(ybr[d]));
    yv[i] = y;
    ssq += y * y;
  }
#pragma unroll
  for (int o = 32; o > 0; o >>= 1) ssq += __shfl_down(ssq, o);
  __shared__ float rb[4];
  int wv = t >> 6, ln = t & 63;
  if (ln == 0) rb[wv] = ssq;
  __syncthreads();
  if (t == 0) rb[0] = rb[0] + rb[1] + rb[2] + rb[3];
  __syncthreads();
  float scale = rsqrtf(rb[0] * (1.f / 512) + 1e-5f);
#pragma unroll
  for (int i = 0; i < 2; i++) {
    int d = t + i * 256;
    yfr[d] = f2bf(yv[i] * scale * in_rd(rms_w, d, isb));
  }
}

extern "C" void kernel_launch(void* const* d_in, const int* in_sizes, int n_in,
                              void* d_out, int out_size, void* d_ws, size_t ws_size,
                              hipStream_t stream) {
  const void* x        = d_in[0];
  const void* ln_w     = d_in[1];
  const void* ln_b     = d_in[2];
  const void* in_proj  = d_in[3];
  const void* conv_w   = d_in[4];
  const void* conv_b   = d_in[5];
  const void* x_proj_w = d_in[6];
  const void* dt_w     = d_in[7];
  const void* dt_b     = d_in[8];
  const void* A_log    = d_in[9];
  const void* Dp       = d_in[10];
  const void* conv_w_b = d_in[11];
  const void* conv_b_b = d_in[12];
  const void* x_proj_b = d_in[13];
  const void* dt_w_b   = d_in[14];
  const void* dt_b_b   = d_in[15];
  const void* A_log_b  = d_in[16];
  const void* Dp_b     = d_in[17];
  const void* rms_w    = d_in[18];
  const void* out_w    = d_in[19];
  (void)in_sizes; (void)n_in; (void)out_size; (void)ws_size;

  char* ws = (char*)d_ws;
  __hip_bfloat16* bufA = (__hip_bfloat16*)(ws + OFF_BUFA);  // h / delta_f / ys_f / ynorm
  __hip_bfloat16* bufB = (__hip_bfloat16*)(ws + OFF_BUFB);  // xm
  __hip_bfloat16* dtb  = (__hip_bfloat16*)(ws + OFF_DT);
  float* Bb = (float*)(ws + OFF_B);
  float* Cb = (float*)(ws + OFF_C);
  float* Pb = (float*)(ws + OFF_P);     // P, then (pass2) H0 in place
  float* Sb = (float*)(ws + OFF_S);
  short* canon = (short*)(ws + OFF_CANON);
  int* flag = (int*)(ws + OFF_FLAG);
  __hip_bfloat16* z    = (__hip_bfloat16*)d_out;                     // d_out lower 16 MiB
  __hip_bfloat16* bufC = (__hip_bfloat16*)((char*)d_out + 16 * MiB); // d_out upper 16 MiB

  probe_kernel<<<dim3(1), dim3(64), 0, stream>>>(x, flag);
  canon_kernel<<<dim3((CN_TOT + 255) / 256), dim3(256), 0, stream>>>(
      flag, in_proj, out_w, x_proj_w, x_proj_b, dt_w, dt_w_b,
      conv_w, conv_w_b, conv_b, conv_b_b, canon);
  ln_kernel<<<dim3(Mr), dim3(256), 0, stream>>>(x, ln_w, ln_b, bufA, flag);
  gemm_nt<0><<<dim3(8, 128), dim3(256), 0, stream>>>(
      bufA, (const __hip_bfloat16*)(canon + CN_INP), bufB, z, nullptr, nullptr, flag);
  xproj_gemm<<<dim3(256, 2), dim3(256), 0, stream>>>(bufB, canon, dtb, Bb, Cb);
  delta_gemm<<<dim3(4, 128, 2), dim3(256), 0, stream>>>(dtb, canon, dt_b, dt_b_b, flag, bufA, bufC);
  scan_pass1<<<dim3(NCH, 8), dim3(512), 0, stream>>>(bufA, bufC, bufB, canon, Bb, Pb, Sb,
                                                     A_log, A_log_b, flag);
  scan_pass2<<<dim3(128), dim3(256), 0, stream>>>(Pb, Sb);
  scan_pass3<<<dim3(NCH, 8), dim3(512), 0, stream>>>(bufA, bufC, bufB, canon, Bb, Cb, Pb,
                                                     A_log, A_log_b, Dp, Dp_b, flag);
  combine_rms<<<dim3(Mr), dim3(256), 0, stream>>>(z, bufA, bufC, rms_w, flag);
  gemm_nt<1><<<dim3(4, 128), dim3(256), 0, stream>>>(
      bufA, (const __hip_bfloat16*)(canon + CN_OUTP), nullptr, nullptr, x, d_out, flag);
}